// Round 1
// baseline (414.175 us; speedup 1.0000x reference)
//
#include <hip/hip_runtime.h>
#include <hip/hip_bf16.h>
#include <stdint.h>

typedef __attribute__((ext_vector_type(8))) short short8;
typedef __attribute__((ext_vector_type(4))) float float4v;

#define NHEADS 4
#define NNODES 4096

__device__ __forceinline__ unsigned short f2b(float x) {
    union { float f; uint32_t u; } v; v.f = x;
    uint32_t u = v.u;
    uint32_t r = (u + 0x7FFFu + ((u >> 16) & 1u)) >> 16;
    return (unsigned short)r;
}
__device__ __forceinline__ float b2f(unsigned short s) {
    union { uint32_t u; float f; } v; v.u = ((uint32_t)s) << 16;
    return v.f;
}

// ---- pack adjacency int32 -> bitmask (1 bit per edge) ----
__global__ __launch_bounds__(256) void k_pack(const int* __restrict__ adj,
                                              unsigned long long* __restrict__ mask) {
    int w = (blockIdx.x * 256 + threadIdx.x) >> 6;
    int lane = threadIdx.x & 63;
    int row = w >> 6;
    int chunk = w & 63;
    int j = chunk * 64 + lane;
    int v = adj[(size_t)row * NNODES + j];
    unsigned long long b = __ballot(v != 0);
    if (lane == 0) mask[row * 64 + chunk] = b;
}

// ---- f32 -> bf16 cast ----
__global__ __launch_bounds__(256) void k_cast(const float* __restrict__ in,
                                              unsigned short* __restrict__ out, int n) {
    int i = blockIdx.x * 256 + threadIdx.x;
    if (i < n) out[i] = f2b(in[i]);
}

// ---- W [H][Fin][O] f32 -> WT [H][O][Fin] bf16 ----
__global__ __launch_bounds__(256) void k_transW(const float* __restrict__ W,
                                                unsigned short* __restrict__ WT,
                                                int Fin, int O) {
    int i = blockIdx.x * 256 + threadIdx.x;
    int total = NHEADS * Fin * O;
    if (i >= total) return;
    int o = i % O;
    int f = (i / O) % Fin;
    int h = i / (O * Fin);
    WT[((size_t)(h * O + o)) * Fin + f] = f2b(W[i]);
}

// ---- Wh = x @ W per head (bf16 MFMA). A:[4096][Fin] bf16, WT:[H][O][Fin] bf16
//      out: Wh f32 [H][4096][O] and WhT bf16 [H][O][4096]
__global__ __launch_bounds__(64) void k_whgemm(const unsigned short* __restrict__ A,
                                               const unsigned short* __restrict__ WT,
                                               float* __restrict__ Wh,
                                               unsigned short* __restrict__ WhT,
                                               int Fin, int O) {
    int rt = blockIdx.x & 255;          // 256 row tiles of 16
    int cg = blockIdx.x >> 8;           // col group of 64 cols
    int lane = threadIdx.x & 63;
    int il = lane & 15, g = lane >> 4;
    int r0 = rt * 16;
    int c0 = cg * 64;
    float4v acc[4] = {};
    for (int k = 0; k < Fin; k += 32) {
        short8 af = *(const short8*)(A + (size_t)(r0 + il) * Fin + k + 8 * g);
#pragma unroll
        for (int ot = 0; ot < 4; ++ot) {
            int col = c0 + ot * 16 + il;          // h*O+o == col
            short8 bf = *(const short8*)(WT + (size_t)col * Fin + k + 8 * g);
            acc[ot] = __builtin_amdgcn_mfma_f32_16x16x32_bf16(af, bf, acc[ot], 0, 0, 0);
        }
    }
#pragma unroll
    for (int ot = 0; ot < 4; ++ot) {
        int col = c0 + ot * 16 + il;
        int h = col / O, o = col % O;
#pragma unroll
        for (int r = 0; r < 4; ++r) {
            int n = r0 + g * 4 + r;
            float v = acc[ot][r];
            Wh[((size_t)h * NNODES + n) * O + o] = v;
            WhT[((size_t)(h * O + o)) * NNODES + n] = f2b(v);
        }
    }
}

// ---- f1[h][n] = Wh[h][n][:] . a[h][:O];  f2 with a[h][O:2O] ----
__global__ __launch_bounds__(256) void k_f1f2(const float* __restrict__ Wh,
                                              const float* __restrict__ a,
                                              float* __restrict__ f1,
                                              float* __restrict__ f2, int O) {
    int item = blockIdx.x * 4 + (threadIdx.x >> 6);
    int lane = threadIdx.x & 63;
    int h = item >> 12;
    int n = item & 4095;
    float w  = (lane < O) ? Wh[((size_t)h * NNODES + n) * O + lane] : 0.f;
    float av1 = (lane < O) ? a[h * 2 * O + lane] : 0.f;
    float av2 = (lane < O) ? a[h * 2 * O + O + lane] : 0.f;
    float s1 = w * av1, s2 = w * av2;
    for (int d = 32; d > 0; d >>= 1) { s1 += __shfl_xor(s1, d); s2 += __shfl_xor(s2, d); }
    if (lane == 0) { f1[h * NNODES + n] = s1; f2[h * NNODES + n] = s2; }
}

// ---- m[h][n] = lrelu(f1[n] + max_{j in N(n)} f2[j]) (exact row max by monotonicity) ----
__global__ __launch_bounds__(256) void k_mrow(const uint32_t* __restrict__ mask,
                                              const float* __restrict__ f1,
                                              const float* __restrict__ f2,
                                              float* __restrict__ mArr) {
    int item = blockIdx.x * 4 + (threadIdx.x >> 6);
    int lane = threadIdx.x & 63;
    int h = item >> 12;
    int n = item & 4095;
    const float* f2h = f2 + h * NNODES;
    const uint32_t* mr = mask + (size_t)n * 128;
    float mx = -3.0e38f;
    for (int t = 0; t < 64; ++t) {
        int j = t * 64 + lane;
        uint32_t wv = mr[j >> 5];
        float v = f2h[j];
        if ((wv >> (j & 31)) & 1u) mx = fmaxf(mx, v);
    }
    for (int d = 32; d > 0; d >>= 1) mx = fmaxf(mx, __shfl_xor(mx, d));
    if (lane == 0) {
        float e = f1[h * NNODES + n] + mx;
        mArr[h * NNODES + n] = fmaxf(e, 0.2f * e);
    }
}

// ---- fused attention: P generated in MFMA A-layout registers, PV via MFMA,
//      row-sum l accumulated inline, epilogue divides + elu + head-concat ----
template <int O>
__global__ __launch_bounds__(256) void k_pv(const uint32_t* __restrict__ mask,
                                            const float* __restrict__ f1,
                                            const float* __restrict__ f2,
                                            const float* __restrict__ mArr,
                                            const unsigned short* __restrict__ WhT,
                                            unsigned short* __restrict__ hout) {
    constexpr int NT = O / 16;
    __shared__ float sacc[4][16][O];
    __shared__ float sl4[4][16];
    int b = blockIdx.x;
    int h = b >> 8;
    int rt = b & 255;
    int wv = threadIdx.x >> 6;
    int lane = threadIdx.x & 63;
    int il = lane & 15, g = lane >> 4;
    int n = rt * 16 + il;
    float f1i = f1[h * NNODES + n];
    float mi = mArr[h * NNODES + n];
    const float* f2h = f2 + h * NNODES;
    const uint32_t* mr = mask + (size_t)n * 128;
    const unsigned short* WB = WhT + (size_t)h * O * NNODES;
    float4v acc[NT];
#pragma unroll
    for (int ot = 0; ot < NT; ++ot) acc[ot] = (float4v){0.f, 0.f, 0.f, 0.f};
    float lsum = 0.f;
    for (int t = 0; t < 32; ++t) {
        int jb = wv * 1024 + t * 32;
        int jl = jb + 8 * g;
        uint32_t mw = mr[jb >> 5];
        uint32_t bits = (mw >> (8 * g)) & 0xFFu;
        float4v fa = *(const float4v*)(f2h + jl);
        float4v fb = *(const float4v*)(f2h + jl + 4);
        short8 pa;
#pragma unroll
        for (int bb = 0; bb < 8; ++bb) {
            float fv = (bb < 4) ? fa[bb] : fb[bb - 4];
            float s = f1i + fv;
            s = fmaxf(s, 0.2f * s);
            float p = ((bits >> bb) & 1u) ? __expf(s - mi) : 0.f;
            lsum += p;
            pa[bb] = (short)f2b(p);
        }
#pragma unroll
        for (int ot = 0; ot < NT; ++ot) {
            short8 bf = *(const short8*)(WB + (size_t)(ot * 16 + il) * NNODES + jl);
            acc[ot] = __builtin_amdgcn_mfma_f32_16x16x32_bf16(pa, bf, acc[ot], 0, 0, 0);
        }
    }
    lsum += __shfl_xor(lsum, 16);
    lsum += __shfl_xor(lsum, 32);
#pragma unroll
    for (int ot = 0; ot < NT; ++ot)
#pragma unroll
        for (int r = 0; r < 4; ++r) sacc[wv][g * 4 + r][ot * 16 + il] = acc[ot][r];
    if (g == 0) sl4[wv][il] = lsum;
    __syncthreads();
    constexpr int HO = NHEADS * O;
    for (int e = threadIdx.x; e < 16 * O; e += 256) {
        int row = e / O;
        int col = e % O;
        float s = sacc[0][row][col] + sacc[1][row][col] + sacc[2][row][col] + sacc[3][row][col];
        float lt = sl4[0][row] + sl4[1][row] + sl4[2][row] + sl4[3][row];
        float v = s / lt;
        v = (v > 0.f) ? v : (__expf(v) - 1.f);
        hout[(size_t)(rt * 16 + row) * HO + h * O + col] = f2b(v);
    }
}

// ---- logits = h3 @ Wlin + blin; log_softmax ----
__global__ __launch_bounds__(256) void k_final(const unsigned short* __restrict__ h3,
                                               const float* __restrict__ Wlin,
                                               const float* __restrict__ blin,
                                               float* __restrict__ out) {
    int n = blockIdx.x * 4 + (threadIdx.x >> 6);
    int lane = threadIdx.x & 63;
    float logit = 0.f;
    if (lane < 40) {
        logit = blin[lane];
        for (int k = 0; k < 64; ++k) {
            logit += b2f(h3[n * 64 + k]) * Wlin[k * 40 + lane];
        }
    }
    float mv = (lane < 40) ? logit : -3.0e38f;
    for (int d = 32; d > 0; d >>= 1) mv = fmaxf(mv, __shfl_xor(mv, d));
    float ex = (lane < 40) ? __expf(logit - mv) : 0.f;
    for (int d = 32; d > 0; d >>= 1) ex += __shfl_xor(ex, d);
    if (lane < 40) out[n * 40 + lane] = logit - mv - logf(ex);
}

static void run_stage(hipStream_t stream, const uint32_t* mask, const unsigned short* xin,
                      const float* W, const float* a, int Fin, int O,
                      unsigned short* WT, float* Wh, unsigned short* WhT,
                      float* f1, float* f2, float* mArr, unsigned short* hout) {
    int total = NHEADS * Fin * O;
    k_transW<<<(total + 255) / 256, 256, 0, stream>>>(W, WT, Fin, O);
    int CG = (NHEADS * O) / 64;
    k_whgemm<<<256 * CG, 64, 0, stream>>>(xin, WT, Wh, WhT, Fin, O);
    k_f1f2<<<4096, 256, 0, stream>>>(Wh, a, f1, f2, O);
    k_mrow<<<4096, 256, 0, stream>>>(mask, f1, f2, mArr);
    if (O == 64)
        k_pv<64><<<1024, 256, 0, stream>>>(mask, f1, f2, mArr, WhT, hout);
    else if (O == 32)
        k_pv<32><<<1024, 256, 0, stream>>>(mask, f1, f2, mArr, WhT, hout);
    else
        k_pv<16><<<1024, 256, 0, stream>>>(mask, f1, f2, mArr, WhT, hout);
}

extern "C" void kernel_launch(void* const* d_in, const int* in_sizes, int n_in,
                              void* d_out, int out_size, void* d_ws, size_t ws_size,
                              hipStream_t stream) {
    const float* x    = (const float*)d_in[0];
    const int*   adj  = (const int*)d_in[1];
    const float* W1   = (const float*)d_in[2];
    const float* a1   = (const float*)d_in[3];
    const float* W2   = (const float*)d_in[4];
    const float* a2   = (const float*)d_in[5];
    const float* W3   = (const float*)d_in[6];
    const float* a3   = (const float*)d_in[7];
    const float* Wlin = (const float*)d_in[8];
    const float* blin = (const float*)d_in[9];
    float* out = (float*)d_out;

    char* ws = (char*)d_ws;
    uint32_t*       mask = (uint32_t*)ws;                                  // 2 MB
    unsigned short* xbf  = (unsigned short*)(ws + (2u << 20));             // 4 MB
    unsigned short* WhT  = (unsigned short*)(ws + (6u << 20));             // 2 MB
    float*          Wh   = (float*)(ws + (8u << 20));                      // 4 MB
    unsigned short* WT   = (unsigned short*)(ws + (12u << 20));            // 256 KB
    float*          f1   = (float*)(ws + (12u << 20) + (256u << 10));      // 64 KB
    float*          f2   = (float*)(ws + (12u << 20) + (320u << 10));      // 64 KB
    float*          mArr = (float*)(ws + (12u << 20) + (384u << 10));      // 64 KB

    // adjacency bitmask
    k_pack<<<65536, 256, 0, stream>>>(adj, (unsigned long long*)mask);
    // x -> bf16
    k_cast<<<(NNODES * 512) / 256, 256, 0, stream>>>(x, xbf, NNODES * 512);

    // stage 1: Fin=512, O=64 -> writes [4096][256] bf16 into xbf
    run_stage(stream, mask, xbf, W1, a1, 512, 64, WT, Wh, WhT, f1, f2, mArr, xbf);
    // stage 2: Fin=256, O=32 -> [4096][128]
    run_stage(stream, mask, xbf, W2, a2, 256, 32, WT, Wh, WhT, f1, f2, mArr, xbf);
    // stage 3: Fin=128, O=16 -> [4096][64]
    run_stage(stream, mask, xbf, W3, a3, 128, 16, WT, Wh, WhT, f1, f2, mArr, xbf);

    // final linear + log_softmax
    k_final<<<NNODES / 4, 256, 0, stream>>>(xbf, Wlin, blin, out);
}

// Round 2
// 210.010 us; speedup vs baseline: 1.9722x; 1.9722x over previous
//
#include <hip/hip_runtime.h>
#include <hip/hip_bf16.h>
#include <stdint.h>

typedef __attribute__((ext_vector_type(8))) short short8;
typedef __attribute__((ext_vector_type(4))) float float4v;

#define NHEADS 4
#define NNODES 4096
#define LOG2E 1.4426950408889634f

__device__ __forceinline__ unsigned short f2b(float x) {
    union { float f; uint32_t u; } v; v.f = x;
    uint32_t u = v.u;
    uint32_t r = (u + 0x7FFFu + ((u >> 16) & 1u)) >> 16;
    return (unsigned short)r;
}
__device__ __forceinline__ float b2f(unsigned short s) {
    union { uint32_t u; float f; } v; v.u = ((uint32_t)s) << 16;
    return v.f;
}
__device__ __forceinline__ uint32_t cvtpk(float lo, float hi) {
    uint32_t r;
    asm("v_cvt_pk_bf16_f32 %0, %1, %2" : "=v"(r) : "v"(lo), "v"(hi));
    return r;
}

// ---- pack adjacency int32 -> bitmask (1 bit per edge) ----
__global__ __launch_bounds__(256) void k_pack(const int* __restrict__ adj,
                                              unsigned long long* __restrict__ mask) {
    int w = (blockIdx.x * 256 + threadIdx.x) >> 6;
    int lane = threadIdx.x & 63;
    int row = w >> 6;
    int chunk = w & 63;
    int j = chunk * 64 + lane;
    int v = adj[(size_t)row * NNODES + j];
    unsigned long long b = __ballot(v != 0);
    if (lane == 0) mask[row * 64 + chunk] = b;
}

// ---- f32 -> bf16 cast, 4 elems/thread ----
__global__ __launch_bounds__(256) void k_cast(const float* __restrict__ in,
                                              unsigned short* __restrict__ out, int n4) {
    int i = blockIdx.x * 256 + threadIdx.x;
    if (i >= n4) return;
    float4v v = ((const float4v*)in)[i];
    uint2 r;
    r.x = cvtpk(v[0], v[1]);
    r.y = cvtpk(v[2], v[3]);
    ((uint2*)out)[i] = r;
}

// ---- W [H][Fin][O] f32 -> WT [H][O][Fin] bf16 ----
__global__ __launch_bounds__(256) void k_transW(const float* __restrict__ W,
                                                unsigned short* __restrict__ WT,
                                                int Fin, int O) {
    int i = blockIdx.x * 256 + threadIdx.x;
    int total = NHEADS * Fin * O;
    if (i >= total) return;
    int o = i % O;
    int f = (i / O) % Fin;
    int h = i / (O * Fin);
    WT[((size_t)(h * O + o)) * Fin + f] = f2b(W[i]);
}

// ---- Wh = x @ W: 4 waves K-split + LDS combine. out Wh f32 [H][N][O], WhT bf16 [H][O][N]
__global__ __launch_bounds__(256) void k_whgemm(const unsigned short* __restrict__ A,
                                                const unsigned short* __restrict__ WT,
                                                float* __restrict__ Wh,
                                                unsigned short* __restrict__ WhT,
                                                int Fin, int O) {
    __shared__ float scc[4][16][64];
    int rt = blockIdx.x & 255, cg = blockIdx.x >> 8;
    int wv = threadIdx.x >> 6, lane = threadIdx.x & 63;
    int il = lane & 15, g = lane >> 4;
    int kpw = Fin >> 2;           // per-wave K chunk (>=32, mult of 32 for Fin in {512,256,128})
    int k0 = wv * kpw;
    float4v acc[4];
#pragma unroll
    for (int ot = 0; ot < 4; ++ot) acc[ot] = (float4v){0.f, 0.f, 0.f, 0.f};
    const unsigned short* Arow = A + (size_t)(rt * 16 + il) * Fin + k0 + 8 * g;
    const unsigned short* Bcol = WT + (size_t)(cg * 64 + il) * Fin + k0 + 8 * g;
    for (int k = 0; k < kpw; k += 32) {
        short8 af = *(const short8*)(Arow + k);
#pragma unroll
        for (int ot = 0; ot < 4; ++ot) {
            short8 bf = *(const short8*)(Bcol + (size_t)ot * 16 * Fin + k);
            acc[ot] = __builtin_amdgcn_mfma_f32_16x16x32_bf16(af, bf, acc[ot], 0, 0, 0);
        }
    }
#pragma unroll
    for (int ot = 0; ot < 4; ++ot)
#pragma unroll
        for (int r = 0; r < 4; ++r) scc[wv][g * 4 + r][ot * 16 + il] = acc[ot][r];
    __syncthreads();
    for (int e = threadIdx.x; e < 1024; e += 256) {
        int row = e >> 6, col = e & 63;
        float v = scc[0][row][col] + scc[1][row][col] + scc[2][row][col] + scc[3][row][col];
        int gc = cg * 64 + col;
        int hh = gc / O, o = gc % O;
        int nn = rt * 16 + row;
        Wh[((size_t)hh * NNODES + nn) * O + o] = v;
        WhT[((size_t)(hh * O + o)) * NNODES + nn] = f2b(v);
    }
}

// ---- f1L/f2L = (Wh . a_src/dst) * log2e ----
__global__ __launch_bounds__(256) void k_f1f2(const float* __restrict__ Wh,
                                              const float* __restrict__ a,
                                              float* __restrict__ f1,
                                              float* __restrict__ f2, int O) {
    int item = blockIdx.x * 4 + (threadIdx.x >> 6);
    int lane = threadIdx.x & 63;
    int h = item >> 12;
    int n = item & 4095;
    float w  = (lane < O) ? Wh[((size_t)h * NNODES + n) * O + lane] : 0.f;
    float av1 = (lane < O) ? a[h * 2 * O + lane] : 0.f;
    float av2 = (lane < O) ? a[h * 2 * O + O + lane] : 0.f;
    float s1 = w * av1, s2 = w * av2;
    for (int d = 32; d > 0; d >>= 1) { s1 += __shfl_xor(s1, d); s2 += __shfl_xor(s2, d); }
    if (lane == 0) { f1[h * NNODES + n] = s1 * LOG2E; f2[h * NNODES + n] = s2 * LOG2E; }
}

// ---- fused attention PV: software-pipelined, LDS-staged f2, ones-column row sums ----
template <int O>
__global__ __launch_bounds__(256, 4) void k_pv(const uint32_t* __restrict__ mask,
                                               const float* __restrict__ f1L,
                                               const float* __restrict__ f2L,
                                               const unsigned short* __restrict__ WhT,
                                               unsigned short* __restrict__ hout) {
    constexpr int NT = O / 16;
    constexpr int HO = NHEADS * O;
    __shared__ float sf2[NNODES];
    __shared__ float sacc[4][16][O];
    __shared__ float sl4[4][16];
    const int h = blockIdx.x >> 8, rt = blockIdx.x & 255;
    const int wv = threadIdx.x >> 6, lane = threadIdx.x & 63;
    const int il = lane & 15, g = lane >> 4;
    const float* f2h = f2L + h * NNODES;
    for (int i = threadIdx.x; i < NNODES / 4; i += 256)
        ((float4v*)sf2)[i] = ((const float4v*)f2h)[i];
    __syncthreads();
    const int n = rt * 16 + il;
    const float f1i = f1L[h * NNODES + n];
    const uint32_t* mrq = (const uint32_t*)mask + (size_t)n * 128 + wv * 32;
    const unsigned short* WB = WhT + ((size_t)h * O + il) * NNODES + wv * 1024 + 8 * g;
    const float* pF = sf2 + wv * 1024 + 8 * g;
    float4v acc[NT];
#pragma unroll
    for (int ot = 0; ot < NT; ++ot) acc[ot] = (float4v){0.f, 0.f, 0.f, 0.f};
    float4v accl = (float4v){0.f, 0.f, 0.f, 0.f};
    short8 bones;
#pragma unroll
    for (int q = 0; q < 8; ++q) bones[q] = (il == 0) ? (short)0x3F80 : (short)0;

    auto loadB = [&](int T, short8* BB) {
#pragma unroll
        for (int ot = 0; ot < NT; ++ot)
            BB[ot] = *(const short8*)(WB + (size_t)ot * 16 * NNODES + T * 32);
    };
    auto comp = [&](uint32_t word, float4v FA, float4v FB, short8* BB) {
        uint32_t bits = (word >> (8 * g)) & 0xFFu;
        float p[8];
#pragma unroll
        for (int b = 0; b < 8; ++b) {
            float s = f1i + ((b < 4) ? FA[b] : FB[b - 4]);
            s = fmaxf(s, 0.2f * s);
            float pv = __builtin_amdgcn_exp2f(s);
            p[b] = ((bits >> b) & 1u) ? pv : 0.f;
        }
        union { short8 s8; uint32_t u[4]; } pu;
        pu.u[0] = cvtpk(p[0], p[1]);
        pu.u[1] = cvtpk(p[2], p[3]);
        pu.u[2] = cvtpk(p[4], p[5]);
        pu.u[3] = cvtpk(p[6], p[7]);
#pragma unroll
        for (int ot = 0; ot < NT; ++ot)
            acc[ot] = __builtin_amdgcn_mfma_f32_16x16x32_bf16(pu.s8, BB[ot], acc[ot], 0, 0, 0);
        accl = __builtin_amdgcn_mfma_f32_16x16x32_bf16(pu.s8, bones, accl, 0, 0, 0);
    };

    float4v fa0, fb0, fa1, fb1;
    short8 B0[NT], B1[NT];
    uint4 mq = *(const uint4*)mrq;
    fa0 = *(const float4v*)(pF);
    fb0 = *(const float4v*)(pF + 4);
    loadB(0, B0);
    for (int t4 = 0; t4 < 8; ++t4) {
        const int tb = 4 * t4;
        uint4 mqn = *(const uint4*)(mrq + tb + 4);  // last iter over-reads 16B into ws scratch: harmless
        fa1 = *(const float4v*)(pF + (tb + 1) * 32);
        fb1 = *(const float4v*)(pF + (tb + 1) * 32 + 4);
        loadB(tb + 1, B1);
        comp(mq.x, fa0, fb0, B0);
        fa0 = *(const float4v*)(pF + (tb + 2) * 32);
        fb0 = *(const float4v*)(pF + (tb + 2) * 32 + 4);
        loadB(tb + 2, B0);
        comp(mq.y, fa1, fb1, B1);
        fa1 = *(const float4v*)(pF + (tb + 3) * 32);
        fb1 = *(const float4v*)(pF + (tb + 3) * 32 + 4);
        loadB(tb + 3, B1);
        comp(mq.z, fa0, fb0, B0);
        fa0 = *(const float4v*)(pF + (tb + 4) * 32);   // last iter over-reads LDS/global: in-bounds scratch
        fb0 = *(const float4v*)(pF + (tb + 4) * 32 + 4);
        loadB(tb + 4, B0);
        comp(mq.w, fa1, fb1, B1);
        mq = mqn;
    }

#pragma unroll
    for (int ot = 0; ot < NT; ++ot)
#pragma unroll
        for (int r = 0; r < 4; ++r) sacc[wv][g * 4 + r][ot * 16 + il] = acc[ot][r];
    if (il == 0) {
#pragma unroll
        for (int r = 0; r < 4; ++r) sl4[wv][g * 4 + r] = accl[r];
    }
    __syncthreads();
    for (int e = threadIdx.x; e < 16 * O; e += 256) {
        int row = e / O, col = e % O;
        float s = sacc[0][row][col] + sacc[1][row][col] + sacc[2][row][col] + sacc[3][row][col];
        float lt = sl4[0][row] + sl4[1][row] + sl4[2][row] + sl4[3][row];
        float v = s / lt;
        v = (v > 0.f) ? v : (__expf(v) - 1.f);
        hout[(size_t)(rt * 16 + row) * HO + h * O + col] = f2b(v);
    }
}

// ---- logits = h3 @ Wlin + blin; log_softmax ----
__global__ __launch_bounds__(256) void k_final(const unsigned short* __restrict__ h3,
                                               const float* __restrict__ Wlin,
                                               const float* __restrict__ blin,
                                               float* __restrict__ out) {
    int n = blockIdx.x * 4 + (threadIdx.x >> 6);
    int lane = threadIdx.x & 63;
    float logit = 0.f;
    if (lane < 40) {
        logit = blin[lane];
        for (int k = 0; k < 64; ++k) {
            logit += b2f(h3[n * 64 + k]) * Wlin[k * 40 + lane];
        }
    }
    float mv = (lane < 40) ? logit : -3.0e38f;
    for (int d = 32; d > 0; d >>= 1) mv = fmaxf(mv, __shfl_xor(mv, d));
    float ex = (lane < 40) ? __expf(logit - mv) : 0.f;
    for (int d = 32; d > 0; d >>= 1) ex += __shfl_xor(ex, d);
    if (lane < 40) out[n * 40 + lane] = logit - mv - logf(ex);
}

static void run_stage(hipStream_t stream, const uint32_t* mask, const unsigned short* xin,
                      const float* W, const float* a, int Fin, int O,
                      unsigned short* WT, float* Wh, unsigned short* WhT,
                      float* f1, float* f2, unsigned short* hout) {
    int total = NHEADS * Fin * O;
    k_transW<<<(total + 255) / 256, 256, 0, stream>>>(W, WT, Fin, O);
    int CG = (NHEADS * O) / 64;
    k_whgemm<<<256 * CG, 256, 0, stream>>>(xin, WT, Wh, WhT, Fin, O);
    k_f1f2<<<4096, 256, 0, stream>>>(Wh, a, f1, f2, O);
    if (O == 64)
        k_pv<64><<<1024, 256, 0, stream>>>(mask, f1, f2, WhT, hout);
    else if (O == 32)
        k_pv<32><<<1024, 256, 0, stream>>>(mask, f1, f2, WhT, hout);
    else
        k_pv<16><<<1024, 256, 0, stream>>>(mask, f1, f2, WhT, hout);
}

extern "C" void kernel_launch(void* const* d_in, const int* in_sizes, int n_in,
                              void* d_out, int out_size, void* d_ws, size_t ws_size,
                              hipStream_t stream) {
    const float* x    = (const float*)d_in[0];
    const int*   adj  = (const int*)d_in[1];
    const float* W1   = (const float*)d_in[2];
    const float* a1   = (const float*)d_in[3];
    const float* W2   = (const float*)d_in[4];
    const float* a2   = (const float*)d_in[5];
    const float* W3   = (const float*)d_in[6];
    const float* a3   = (const float*)d_in[7];
    const float* Wlin = (const float*)d_in[8];
    const float* blin = (const float*)d_in[9];
    float* out = (float*)d_out;

    char* ws = (char*)d_ws;
    uint32_t*       mask = (uint32_t*)ws;                                  // 2 MB
    unsigned short* xbf  = (unsigned short*)(ws + (2u << 20));             // 4 MB
    unsigned short* WhT  = (unsigned short*)(ws + (6u << 20));             // 2 MB
    float*          Wh   = (float*)(ws + (8u << 20));                      // 4 MB
    unsigned short* WT   = (unsigned short*)(ws + (12u << 20));            // 256 KB
    float*          f1   = (float*)(ws + (12u << 20) + (256u << 10));      // 64 KB
    float*          f2   = (float*)(ws + (12u << 20) + (320u << 10));      // 64 KB

    k_pack<<<65536, 256, 0, stream>>>(adj, (unsigned long long*)mask);
    k_cast<<<(NNODES * 512 / 4 + 255) / 256, 256, 0, stream>>>(x, xbf, NNODES * 512 / 4);

    run_stage(stream, mask, xbf, W1, a1, 512, 64, WT, Wh, WhT, f1, f2, xbf);
    run_stage(stream, mask, xbf, W2, a2, 256, 32, WT, Wh, WhT, f1, f2, xbf);
    run_stage(stream, mask, xbf, W3, a3, 128, 16, WT, Wh, WhT, f1, f2, xbf);

    k_final<<<NNODES / 4, 256, 0, stream>>>(xbf, Wlin, blin, out);
}

// Round 3
// 192.114 us; speedup vs baseline: 2.1559x; 1.0932x over previous
//
#include <hip/hip_runtime.h>
#include <hip/hip_bf16.h>
#include <stdint.h>

typedef __attribute__((ext_vector_type(8))) short short8;
typedef __attribute__((ext_vector_type(4))) float float4v;

#define NHEADS 4
#define NNODES 4096
#define LOG2E 1.4426950408889634f

__device__ __forceinline__ unsigned short f2b(float x) {
    union { float f; uint32_t u; } v; v.f = x;
    uint32_t u = v.u;
    uint32_t r = (u + 0x7FFFu + ((u >> 16) & 1u)) >> 16;
    return (unsigned short)r;
}
__device__ __forceinline__ float b2f(unsigned short s) {
    union { uint32_t u; float f; } v; v.u = ((uint32_t)s) << 16;
    return v.f;
}
__device__ __forceinline__ uint32_t cvtpk(float lo, float hi) {
    uint32_t r;
    asm("v_cvt_pk_bf16_f32 %0, %1, %2" : "=v"(r) : "v"(lo), "v"(hi));
    return r;
}

#define AS1 __attribute__((address_space(1)))
#define AS3 __attribute__((address_space(3)))
__device__ __forceinline__ void gl_lds16(const void* g, void* l) {
    __builtin_amdgcn_global_load_lds((const AS1 unsigned int*)g,
                                     (AS3 unsigned int*)l, 16, 0, 0);
}

// ---- pack adjacency int32 -> bitmask ----
__global__ __launch_bounds__(256) void k_pack(const int* __restrict__ adj,
                                              unsigned long long* __restrict__ mask) {
    int w = (blockIdx.x * 256 + threadIdx.x) >> 6;
    int lane = threadIdx.x & 63;
    int row = w >> 6;
    int chunk = w & 63;
    int j = chunk * 64 + lane;
    int v = adj[(size_t)row * NNODES + j];
    unsigned long long b = __ballot(v != 0);
    if (lane == 0) mask[row * 64 + chunk] = b;
}

// ---- f32 -> bf16 cast, 4/thread ----
__global__ __launch_bounds__(256) void k_cast(const float* __restrict__ in,
                                              unsigned short* __restrict__ out, int n4) {
    int i = blockIdx.x * 256 + threadIdx.x;
    if (i >= n4) return;
    float4v v = ((const float4v*)in)[i];
    uint2 r;
    r.x = cvtpk(v[0], v[1]);
    r.y = cvtpk(v[2], v[3]);
    ((uint2*)out)[i] = r;
}

// ---- W [H][Fin][O] f32 -> WT [H][O][Fin] bf16 ----
__global__ __launch_bounds__(256) void k_transW(const float* __restrict__ W,
                                                unsigned short* __restrict__ WT,
                                                int Fin, int O) {
    int i = blockIdx.x * 256 + threadIdx.x;
    int total = NHEADS * Fin * O;
    if (i >= total) return;
    int o = i % O;
    int f = (i / O) % Fin;
    int h = i / (O * Fin);
    WT[((size_t)(h * O + o)) * Fin + f] = f2b(W[i]);
}

// ---- Wh = x @ W: 4 waves K-split + LDS combine ----
__global__ __launch_bounds__(256) void k_whgemm(const unsigned short* __restrict__ A,
                                                const unsigned short* __restrict__ WT,
                                                float* __restrict__ Wh,
                                                unsigned short* __restrict__ WhT,
                                                int Fin, int O) {
    __shared__ float scc[4][16][64];
    int rt = blockIdx.x & 255, cg = blockIdx.x >> 8;
    int wv = threadIdx.x >> 6, lane = threadIdx.x & 63;
    int il = lane & 15, g = lane >> 4;
    int kpw = Fin >> 2;
    int k0 = wv * kpw;
    float4v acc[4];
#pragma unroll
    for (int ot = 0; ot < 4; ++ot) acc[ot] = (float4v){0.f, 0.f, 0.f, 0.f};
    const unsigned short* Arow = A + (size_t)(rt * 16 + il) * Fin + k0 + 8 * g;
    const unsigned short* Bcol = WT + (size_t)(cg * 64 + il) * Fin + k0 + 8 * g;
    for (int k = 0; k < kpw; k += 32) {
        short8 af = *(const short8*)(Arow + k);
#pragma unroll
        for (int ot = 0; ot < 4; ++ot) {
            short8 bf = *(const short8*)(Bcol + (size_t)ot * 16 * Fin + k);
            acc[ot] = __builtin_amdgcn_mfma_f32_16x16x32_bf16(af, bf, acc[ot], 0, 0, 0);
        }
    }
#pragma unroll
    for (int ot = 0; ot < 4; ++ot)
#pragma unroll
        for (int r = 0; r < 4; ++r) scc[wv][g * 4 + r][ot * 16 + il] = acc[ot][r];
    __syncthreads();
    for (int e = threadIdx.x; e < 1024; e += 256) {
        int row = e >> 6, col = e & 63;
        float v = scc[0][row][col] + scc[1][row][col] + scc[2][row][col] + scc[3][row][col];
        int gc = cg * 64 + col;
        int hh = gc / O, o = gc % O;
        int nn = rt * 16 + row;
        Wh[((size_t)hh * NNODES + nn) * O + o] = v;
        WhT[((size_t)(hh * O + o)) * NNODES + nn] = f2b(v);
    }
}

// ---- f1L/f2L = (Wh . a_src/dst) * log2e ----
__global__ __launch_bounds__(256) void k_f1f2(const float* __restrict__ Wh,
                                              const float* __restrict__ a,
                                              float* __restrict__ f1,
                                              float* __restrict__ f2, int O) {
    int item = blockIdx.x * 4 + (threadIdx.x >> 6);
    int lane = threadIdx.x & 63;
    int h = item >> 12;
    int n = item & 4095;
    float w  = (lane < O) ? Wh[((size_t)h * NNODES + n) * O + lane] : 0.f;
    float av1 = (lane < O) ? a[h * 2 * O + lane] : 0.f;
    float av2 = (lane < O) ? a[h * 2 * O + O + lane] : 0.f;
    float s1 = w * av1, s2 = w * av2;
    for (int d = 32; d > 0; d >>= 1) { s1 += __shfl_xor(s1, d); s2 += __shfl_xor(s2, d); }
    if (lane == 0) { f1[h * NNODES + n] = s1 * LOG2E; f2[h * NNODES + n] = s2 * LOG2E; }
}

// ---- stage one 64-j B tile ([O rows][64 j] bf16) into LDS, source-swizzled ----
template <int O>
__device__ __forceinline__ void stage_tile(const unsigned short* WB0, int j0,
                                           char* dst, int tid) {
    constexpr int CH = O * 8;   // 16B chunks
#pragma unroll
    for (int q = 0; q < CH; q += 256) {
        int s = q + tid;
        if (s < CH) {
            int o = s >> 3, c = s & 7;
            int cg = c ^ (o & 7);
            gl_lds16(WB0 + (size_t)o * NNODES + j0 + 8 * cg, dst + s * 16);
        }
    }
}

// ---- fused attention PV: 64 rows/block, shared dbuf B tile, atomic j-split combine ----
template <int O>
__global__ __launch_bounds__(256, 6) void k_pv(const uint32_t* __restrict__ mask,
                                               const float* __restrict__ f1L,
                                               const float* __restrict__ f2L,
                                               const unsigned short* __restrict__ WhT,
                                               float* __restrict__ accum,
                                               float* __restrict__ laccum) {
    constexpr int NT = O / 16;
    constexpr int CH = O * 8;
    __shared__ unsigned short bt[2][CH * 8];
    __shared__ float sf2[1024];
    const int b = blockIdx.x;
    const int js = b & 3, rt = (b >> 2) & 63, h = b >> 8;
    const int tid = threadIdx.x, wv = tid >> 6, lane = tid & 63;
    const int il = lane & 15, g = lane >> 4;
    const int j0b = js * 1024;
    const float* f2h = f2L + h * NNODES;
    const unsigned short* WB0 = WhT + (size_t)h * O * NNODES;
    const int n = rt * 64 + wv * 16 + il;
    const float f1i = f1L[h * NNODES + n];
    const uint32_t* mr = mask + (size_t)n * 128 + js * 32;

    // prologue: stage f2 slice (4KB) + tile 0
    gl_lds16(f2h + j0b + tid * 4, (char*)sf2 + tid * 16);
    stage_tile<O>(WB0, j0b, (char*)&bt[0][0], tid);
    uint2 mw = *(const uint2*)mr;
    __syncthreads();

    float4v acc[NT];
#pragma unroll
    for (int ot = 0; ot < NT; ++ot) acc[ot] = (float4v){0.f, 0.f, 0.f, 0.f};
    float4v accl = (float4v){0.f, 0.f, 0.f, 0.f};
    short8 bones;
#pragma unroll
    for (int q = 0; q < 8; ++q) bones[q] = (il == 0) ? (short)0x3F80 : (short)0;

    int cur = 0;
    for (int t = 0; t < 16; ++t) {
        if (t < 15) stage_tile<O>(WB0, j0b + (t + 1) * 64, (char*)&bt[cur ^ 1][0], tid);
        uint2 mwn = mw;
        if (t < 15) mwn = *(const uint2*)(mr + (t + 1) * 2);
        const char* btc = (const char*)&bt[cur][0];
        const float* fp0 = sf2 + t * 64 + 8 * g;
#pragma unroll
        for (int s = 0; s < 2; ++s) {
            short8 B[NT];
#pragma unroll
            for (int ot = 0; ot < NT; ++ot) {
                int o = ot * 16 + il;
                B[ot] = *(const short8*)(btc + o * 128 + 16 * (((s << 2) + g) ^ (il & 7)));
            }
            const float* fp = fp0 + s * 32;
            float4v fa = *(const float4v*)fp;
            float4v fb = *(const float4v*)(fp + 4);
            uint32_t word = s ? mw.y : mw.x;
            uint32_t bits = (word >> (8 * g)) & 0xFFu;
            float p[8];
#pragma unroll
            for (int bb = 0; bb < 8; ++bb) {
                float sv = f1i + ((bb < 4) ? fa[bb] : fb[bb - 4]);
                sv = fmaxf(sv, 0.2f * sv);
                float pv = __builtin_amdgcn_exp2f(sv);
                p[bb] = ((bits >> bb) & 1u) ? pv : 0.f;
            }
            union { short8 s8; uint32_t u[4]; } pu;
            pu.u[0] = cvtpk(p[0], p[1]);
            pu.u[1] = cvtpk(p[2], p[3]);
            pu.u[2] = cvtpk(p[4], p[5]);
            pu.u[3] = cvtpk(p[6], p[7]);
#pragma unroll
            for (int ot = 0; ot < NT; ++ot)
                acc[ot] = __builtin_amdgcn_mfma_f32_16x16x32_bf16(pu.s8, B[ot], acc[ot], 0, 0, 0);
            accl = __builtin_amdgcn_mfma_f32_16x16x32_bf16(pu.s8, bones, accl, 0, 0, 0);
        }
        __syncthreads();
        cur ^= 1;
        mw = mwn;
    }

    // atomic combine across 4 j-slices
    float* acch = accum + (size_t)h * NNODES * O;
#pragma unroll
    for (int ot = 0; ot < NT; ++ot)
#pragma unroll
        for (int r = 0; r < 4; ++r)
            atomicAdd(&acch[(size_t)(rt * 64 + wv * 16 + g * 4 + r) * O + ot * 16 + il],
                      acc[ot][r]);
    if (il == 0) {
#pragma unroll
        for (int r = 0; r < 4; ++r)
            atomicAdd(&laccum[h * NNODES + rt * 64 + wv * 16 + g * 4 + r], accl[r]);
    }
}

// ---- finalize: divide, elu, head-concat to bf16 ----
template <int O>
__global__ __launch_bounds__(256) void k_fin(const float* __restrict__ accum,
                                             const float* __restrict__ laccum,
                                             unsigned short* __restrict__ hout) {
    constexpr int HO = NHEADS * O;
    int e = blockIdx.x * 256 + threadIdx.x;
    int o = e % O;
    int n = (e / O) & (NNODES - 1);
    int h = e / (O * NNODES);
    float v = accum[((size_t)h * NNODES + n) * O + o] / laccum[h * NNODES + n];
    v = (v > 0.f) ? v : (__expf(v) - 1.f);
    hout[(size_t)n * HO + h * O + o] = f2b(v);
}

// ---- logits = h3 @ Wlin + blin; log_softmax ----
__global__ __launch_bounds__(256) void k_final(const unsigned short* __restrict__ h3,
                                               const float* __restrict__ Wlin,
                                               const float* __restrict__ blin,
                                               float* __restrict__ out) {
    int n = blockIdx.x * 4 + (threadIdx.x >> 6);
    int lane = threadIdx.x & 63;
    float logit = 0.f;
    if (lane < 40) {
        logit = blin[lane];
        for (int k = 0; k < 64; ++k) {
            logit += b2f(h3[n * 64 + k]) * Wlin[k * 40 + lane];
        }
    }
    float mv = (lane < 40) ? logit : -3.0e38f;
    for (int d = 32; d > 0; d >>= 1) mv = fmaxf(mv, __shfl_xor(mv, d));
    float ex = (lane < 40) ? __expf(logit - mv) : 0.f;
    for (int d = 32; d > 0; d >>= 1) ex += __shfl_xor(ex, d);
    if (lane < 40) out[n * 40 + lane] = logit - mv - logf(ex);
}

static void run_stage(hipStream_t stream, const uint32_t* mask, const unsigned short* xin,
                      const float* W, const float* a, int Fin, int O,
                      unsigned short* WT, float* Wh, unsigned short* WhT,
                      float* f1, float* f2, float* lacc, unsigned short* hout) {
    int total = NHEADS * Fin * O;
    k_transW<<<(total + 255) / 256, 256, 0, stream>>>(W, WT, Fin, O);
    int CG = (NHEADS * O) / 64;
    k_whgemm<<<256 * CG, 256, 0, stream>>>(xin, WT, Wh, WhT, Fin, O);
    k_f1f2<<<4096, 256, 0, stream>>>(Wh, a, f1, f2, O);
    // reuse Wh region as the f32 attention accumulator (f1f2 is done with it)
    hipMemsetAsync(Wh, 0, (size_t)NHEADS * NNODES * O * 4, stream);
    hipMemsetAsync(lacc, 0, NHEADS * NNODES * 4, stream);
    if (O == 64) {
        k_pv<64><<<1024, 256, 0, stream>>>(mask, f1, f2, WhT, Wh, lacc);
        k_fin<64><<<NHEADS * NNODES * 64 / 256, 256, 0, stream>>>(Wh, lacc, hout);
    } else if (O == 32) {
        k_pv<32><<<1024, 256, 0, stream>>>(mask, f1, f2, WhT, Wh, lacc);
        k_fin<32><<<NHEADS * NNODES * 32 / 256, 256, 0, stream>>>(Wh, lacc, hout);
    } else {
        k_pv<16><<<1024, 256, 0, stream>>>(mask, f1, f2, WhT, Wh, lacc);
        k_fin<16><<<NHEADS * NNODES * 16 / 256, 256, 0, stream>>>(Wh, lacc, hout);
    }
}

extern "C" void kernel_launch(void* const* d_in, const int* in_sizes, int n_in,
                              void* d_out, int out_size, void* d_ws, size_t ws_size,
                              hipStream_t stream) {
    const float* x    = (const float*)d_in[0];
    const int*   adj  = (const int*)d_in[1];
    const float* W1   = (const float*)d_in[2];
    const float* a1   = (const float*)d_in[3];
    const float* W2   = (const float*)d_in[4];
    const float* a2   = (const float*)d_in[5];
    const float* W3   = (const float*)d_in[6];
    const float* a3   = (const float*)d_in[7];
    const float* Wlin = (const float*)d_in[8];
    const float* blin = (const float*)d_in[9];
    float* out = (float*)d_out;

    char* ws = (char*)d_ws;
    uint32_t*       mask = (uint32_t*)ws;                                  // 2 MB
    unsigned short* xbf  = (unsigned short*)(ws + (2u << 20));             // 4 MB
    unsigned short* WhT  = (unsigned short*)(ws + (6u << 20));             // 2 MB
    float*          Wh   = (float*)(ws + (8u << 20));                      // 4 MB (also attn accum)
    unsigned short* WT   = (unsigned short*)(ws + (12u << 20));            // 256 KB
    float*          f1   = (float*)(ws + (12u << 20) + (256u << 10));      // 64 KB
    float*          f2   = (float*)(ws + (12u << 20) + (320u << 10));      // 64 KB
    float*          lacc = (float*)(ws + (12u << 20) + (384u << 10));      // 64 KB

    k_pack<<<65536, 256, 0, stream>>>(adj, (unsigned long long*)mask);
    k_cast<<<(NNODES * 512 / 4 + 255) / 256, 256, 0, stream>>>(x, xbf, NNODES * 512 / 4);

    run_stage(stream, mask, xbf, W1, a1, 512, 64, WT, Wh, WhT, f1, f2, lacc, xbf);
    run_stage(stream, mask, xbf, W2, a2, 256, 32, WT, Wh, WhT, f1, f2, lacc, xbf);
    run_stage(stream, mask, xbf, W3, a3, 128, 16, WT, Wh, WhT, f1, f2, lacc, xbf);

    k_final<<<NNODES / 4, 256, 0, stream>>>(xbf, Wlin, blin, out);
}

// Round 4
// 158.280 us; speedup vs baseline: 2.6167x; 1.2138x over previous
//
#include <hip/hip_runtime.h>
#include <hip/hip_bf16.h>
#include <stdint.h>

typedef __attribute__((ext_vector_type(8))) short short8;
typedef __attribute__((ext_vector_type(4))) float float4v;

#define NHEADS 4
#define NNODES 4096
#define LOG2E 1.4426950408889634f
#define PSTR ((size_t)NHEADS * NNODES * 64)   // partial-accum stride (floats)
#define LSTR ((size_t)NHEADS * NNODES)        // partial-l stride (floats)

__device__ __forceinline__ unsigned short f2b(float x) {
    union { float f; uint32_t u; } v; v.f = x;
    uint32_t u = v.u;
    uint32_t r = (u + 0x7FFFu + ((u >> 16) & 1u)) >> 16;
    return (unsigned short)r;
}
__device__ __forceinline__ float b2f(unsigned short s) {
    union { uint32_t u; float f; } v; v.u = ((uint32_t)s) << 16;
    return v.f;
}
__device__ __forceinline__ uint32_t cvtpk(float lo, float hi) {
    uint32_t r;
    asm("v_cvt_pk_bf16_f32 %0, %1, %2" : "=v"(r) : "v"(lo), "v"(hi));
    return r;
}

#define AS1 __attribute__((address_space(1)))
#define AS3 __attribute__((address_space(3)))
__device__ __forceinline__ void gl_lds16(const void* g, void* l) {
    __builtin_amdgcn_global_load_lds((const AS1 unsigned int*)g,
                                     (AS3 unsigned int*)l, 16, 0, 0);
}

// ---- pack adjacency int32 -> bitmask ----
__global__ __launch_bounds__(256) void k_pack(const int* __restrict__ adj,
                                              unsigned long long* __restrict__ mask) {
    int w = (blockIdx.x * 256 + threadIdx.x) >> 6;
    int lane = threadIdx.x & 63;
    int row = w >> 6;
    int chunk = w & 63;
    int j = chunk * 64 + lane;
    int v = adj[(size_t)row * NNODES + j];
    unsigned long long b = __ballot(v != 0);
    if (lane == 0) mask[row * 64 + chunk] = b;
}

// ---- one-shot conversions: x cast (4/thread) + W1/W2/W3 transpose-cast ----
__global__ __launch_bounds__(256) void k_convert(const float* __restrict__ x,
                                                 unsigned short* __restrict__ xbf,
                                                 const float* __restrict__ W1,
                                                 unsigned short* __restrict__ WT1,
                                                 const float* __restrict__ W2,
                                                 unsigned short* __restrict__ WT2,
                                                 const float* __restrict__ W3,
                                                 unsigned short* __restrict__ WT3) {
    int i = blockIdx.x * 256 + threadIdx.x;
    if (i < 524288) {                       // x: 4096*512 f32, 4 per thread
        float4v v = ((const float4v*)x)[i];
        uint2 r;
        r.x = cvtpk(v[0], v[1]);
        r.y = cvtpk(v[2], v[3]);
        ((uint2*)xbf)[i] = r;
    } else if (i < 524288 + 131072) {       // W1 [4][512][64] -> WT1 [4][64][512]
        int j = i - 524288;
        int o = j & 63, f = (j >> 6) & 511, h = j >> 15;
        WT1[((size_t)(h * 64 + o)) * 512 + f] = f2b(W1[j]);
    } else if (i < 524288 + 131072 + 32768) { // W2 [4][256][32] -> WT2 [4][32][256]
        int j = i - 655360;
        int o = j & 31, f = (j >> 5) & 255, h = j >> 13;
        WT2[((size_t)(h * 32 + o)) * 256 + f] = f2b(W2[j]);
    } else {                                  // W3 [4][128][16] -> WT3 [4][16][128]
        int j = i - 688128;
        int o = j & 15, f = (j >> 4) & 127, h = j >> 11;
        WT3[((size_t)(h * 16 + o)) * 128 + f] = f2b(W3[j]);
    }
}

// ---- Wh = x @ W (4-wave K-split) + fused f1/f2 epilogue; writes WhT bf16 only ----
template <int Fin, int O>
__global__ __launch_bounds__(256) void k_whgemm(const unsigned short* __restrict__ A,
                                                const unsigned short* __restrict__ WT,
                                                const float* __restrict__ avec,
                                                unsigned short* __restrict__ WhT,
                                                float* __restrict__ f1,
                                                float* __restrict__ f2) {
    __shared__ float scc[4][16][64];
    constexpr int HPB = 64 / O;           // complete heads per col-group
    const int rt = blockIdx.x & 255, cg = blockIdx.x >> 8;
    const int wv = threadIdx.x >> 6, lane = threadIdx.x & 63;
    const int il = lane & 15, g = lane >> 4;
    constexpr int kpw = Fin >> 2;
    const int k0 = wv * kpw;
    float4v acc[4];
#pragma unroll
    for (int ot = 0; ot < 4; ++ot) acc[ot] = (float4v){0.f, 0.f, 0.f, 0.f};
    const unsigned short* Arow = A + (size_t)(rt * 16 + il) * Fin + k0 + 8 * g;
    const unsigned short* Bcol = WT + (size_t)(cg * 64 + il) * Fin + k0 + 8 * g;
#pragma unroll
    for (int k = 0; k < kpw; k += 32) {
        short8 af = *(const short8*)(Arow + k);
#pragma unroll
        for (int ot = 0; ot < 4; ++ot) {
            short8 bf = *(const short8*)(Bcol + (size_t)ot * 16 * Fin + k);
            acc[ot] = __builtin_amdgcn_mfma_f32_16x16x32_bf16(af, bf, acc[ot], 0, 0, 0);
        }
    }
#pragma unroll
    for (int ot = 0; ot < 4; ++ot)
#pragma unroll
        for (int r = 0; r < 4; ++r) scc[wv][g * 4 + r][ot * 16 + il] = acc[ot][r];
    __syncthreads();
    // epilogue 1: WhT bf16 [H][O][N]
    for (int e = threadIdx.x; e < 1024; e += 256) {
        int row = e >> 6, col = e & 63;
        float v = scc[0][row][col] + scc[1][row][col] + scc[2][row][col] + scc[3][row][col];
        int gc = cg * 64 + col;
        int hh = gc / O, o = gc % O;
        WhT[((size_t)(hh * O + o)) * NNODES + rt * 16 + row] = f2b(v);
    }
    // epilogue 2: f1/f2 (each block covers complete heads -> no atomics)
    {
        int hl = lane / O, o = lane % O;
        int h = cg * HPB + hl;
        float av1 = avec[h * 2 * O + o];
        float av2 = avec[h * 2 * O + O + o];
#pragma unroll
        for (int r = 0; r < 4; ++r) {
            int row = wv * 4 + r;
            float v = scc[0][row][lane] + scc[1][row][lane] + scc[2][row][lane] + scc[3][row][lane];
            float s1 = v * av1, s2 = v * av2;
#pragma unroll
            for (int d = O / 2; d > 0; d >>= 1) {
                s1 += __shfl_xor(s1, d);
                s2 += __shfl_xor(s2, d);
            }
            if (o == 0) {
                int n = rt * 16 + row;
                f1[h * NNODES + n] = s1 * LOG2E;
                f2[h * NNODES + n] = s2 * LOG2E;
            }
        }
    }
}

// ---- stage one 64-j B tile ([O rows][64 j] bf16) into LDS, source-swizzled ----
template <int O>
__device__ __forceinline__ void stage_tile(const unsigned short* WB0, int j0,
                                           char* dst, int tid) {
    constexpr int CH = O * 8;   // 16B chunks
#pragma unroll
    for (int q = 0; q < CH; q += 256) {
        int s = q + tid;
        if (s < CH) {
            int o = s >> 3, c = s & 7;
            int cg = c ^ (o & 7);
            gl_lds16(WB0 + (size_t)o * NNODES + j0 + 8 * cg, dst + s * 16);
        }
    }
}

// ---- fused attention PV: 64 rows/block, shared dbuf B tile, disjoint j-split partials ----
template <int O>
__global__ __launch_bounds__(256, 6) void k_pv(const uint32_t* __restrict__ mask,
                                               const float* __restrict__ f1L,
                                               const float* __restrict__ f2L,
                                               const unsigned short* __restrict__ WhT,
                                               float* __restrict__ pacc,
                                               float* __restrict__ lpart) {
    constexpr int NT = O / 16;
    constexpr int CH = O * 8;
    __shared__ unsigned short bt[2][CH * 8];
    __shared__ float sf2[1024];
    const int b = blockIdx.x;
    const int js = b & 3, rt = (b >> 2) & 63, h = b >> 8;
    const int tid = threadIdx.x, wv = tid >> 6, lane = tid & 63;
    const int il = lane & 15, g = lane >> 4;
    const int j0b = js * 1024;
    const float* f2h = f2L + h * NNODES;
    const unsigned short* WB0 = WhT + (size_t)h * O * NNODES;
    const int n = rt * 64 + wv * 16 + il;
    const float f1i = f1L[h * NNODES + n];
    const uint32_t* mr = mask + (size_t)n * 128 + js * 32;

    gl_lds16(f2h + j0b + tid * 4, (char*)sf2 + tid * 16);
    stage_tile<O>(WB0, j0b, (char*)&bt[0][0], tid);
    uint2 mw = *(const uint2*)mr;
    __syncthreads();

    float4v acc[NT];
#pragma unroll
    for (int ot = 0; ot < NT; ++ot) acc[ot] = (float4v){0.f, 0.f, 0.f, 0.f};
    float4v accl = (float4v){0.f, 0.f, 0.f, 0.f};
    short8 bones;
#pragma unroll
    for (int q = 0; q < 8; ++q) bones[q] = (il == 0) ? (short)0x3F80 : (short)0;

    int cur = 0;
    for (int t = 0; t < 16; ++t) {
        if (t < 15) stage_tile<O>(WB0, j0b + (t + 1) * 64, (char*)&bt[cur ^ 1][0], tid);
        uint2 mwn = mw;
        if (t < 15) mwn = *(const uint2*)(mr + (t + 1) * 2);
        const char* btc = (const char*)&bt[cur][0];
        const float* fp0 = sf2 + t * 64 + 8 * g;
#pragma unroll
        for (int s = 0; s < 2; ++s) {
            short8 B[NT];
#pragma unroll
            for (int ot = 0; ot < NT; ++ot) {
                int o = ot * 16 + il;
                B[ot] = *(const short8*)(btc + o * 128 + 16 * (((s << 2) + g) ^ (il & 7)));
            }
            const float* fp = fp0 + s * 32;
            float4v fa = *(const float4v*)fp;
            float4v fb = *(const float4v*)(fp + 4);
            uint32_t word = s ? mw.y : mw.x;
            uint32_t bits = (word >> (8 * g)) & 0xFFu;
            float p[8];
#pragma unroll
            for (int bb = 0; bb < 8; ++bb) {
                float sv = f1i + ((bb < 4) ? fa[bb] : fb[bb - 4]);
                sv = fmaxf(sv, 0.2f * sv);
                float pv = __builtin_amdgcn_exp2f(sv);
                p[bb] = ((bits >> bb) & 1u) ? pv : 0.f;
            }
            union { short8 s8; uint32_t u[4]; } pu;
            pu.u[0] = cvtpk(p[0], p[1]);
            pu.u[1] = cvtpk(p[2], p[3]);
            pu.u[2] = cvtpk(p[4], p[5]);
            pu.u[3] = cvtpk(p[6], p[7]);
#pragma unroll
            for (int ot = 0; ot < NT; ++ot)
                acc[ot] = __builtin_amdgcn_mfma_f32_16x16x32_bf16(pu.s8, B[ot], acc[ot], 0, 0, 0);
            accl = __builtin_amdgcn_mfma_f32_16x16x32_bf16(pu.s8, bones, accl, 0, 0, 0);
        }
        __syncthreads();
        cur ^= 1;
        mw = mwn;
    }

    // non-atomic disjoint partial stores (slice js owns its buffer)
    float* pj = pacc + js * PSTR + (size_t)h * NNODES * O;
#pragma unroll
    for (int ot = 0; ot < NT; ++ot)
#pragma unroll
        for (int r = 0; r < 4; ++r)
            pj[(size_t)(rt * 64 + wv * 16 + g * 4 + r) * O + ot * 16 + il] = acc[ot][r];
    if (il == 0) {
        float* lj = lpart + js * LSTR + h * NNODES;
#pragma unroll
        for (int r = 0; r < 4; ++r)
            lj[rt * 64 + wv * 16 + g * 4 + r] = accl[r];
    }
}

// ---- finalize: sum 4 partials, divide, elu, head-concat to bf16 ----
template <int O>
__global__ __launch_bounds__(256) void k_fin(const float* __restrict__ pacc,
                                             const float* __restrict__ lpart,
                                             unsigned short* __restrict__ hout) {
    constexpr int HO = NHEADS * O;
    int e = blockIdx.x * 256 + threadIdx.x;
    int o = e % O;
    int n = (e / O) & (NNODES - 1);
    int h = e / (O * NNODES);
    size_t idx = ((size_t)h * NNODES + n) * O + o;
    float s = pacc[idx] + pacc[PSTR + idx] + pacc[2 * PSTR + idx] + pacc[3 * PSTR + idx];
    int li = h * NNODES + n;
    float l = lpart[li] + lpart[LSTR + li] + lpart[2 * LSTR + li] + lpart[3 * LSTR + li];
    float v = s / l;
    v = (v > 0.f) ? v : (__expf(v) - 1.f);
    hout[(size_t)n * HO + h * O + o] = f2b(v);
}

// ---- logits = h3 @ Wlin + blin; log_softmax ----
__global__ __launch_bounds__(256) void k_final(const unsigned short* __restrict__ h3,
                                               const float* __restrict__ Wlin,
                                               const float* __restrict__ blin,
                                               float* __restrict__ out) {
    int n = blockIdx.x * 4 + (threadIdx.x >> 6);
    int lane = threadIdx.x & 63;
    float logit = 0.f;
    if (lane < 40) {
        logit = blin[lane];
        for (int k = 0; k < 64; ++k) {
            logit += b2f(h3[n * 64 + k]) * Wlin[k * 40 + lane];
        }
    }
    float mv = (lane < 40) ? logit : -3.0e38f;
    for (int d = 32; d > 0; d >>= 1) mv = fmaxf(mv, __shfl_xor(mv, d));
    float ex = (lane < 40) ? __expf(logit - mv) : 0.f;
    for (int d = 32; d > 0; d >>= 1) ex += __shfl_xor(ex, d);
    if (lane < 40) out[n * 40 + lane] = logit - mv - logf(ex);
}

template <int Fin, int O>
static void run_stage(hipStream_t stream, const uint32_t* mask, const unsigned short* xin,
                      const unsigned short* WT, const float* avec,
                      unsigned short* WhT, float* f1, float* f2,
                      float* pacc, float* lpart, unsigned short* hout) {
    constexpr int CG = (NHEADS * O) / 64;
    k_whgemm<Fin, O><<<256 * CG, 256, 0, stream>>>(xin, WT, avec, WhT, f1, f2);
    k_pv<O><<<1024, 256, 0, stream>>>(mask, f1, f2, WhT, pacc, lpart);
    k_fin<O><<<NHEADS * NNODES * O / 256, 256, 0, stream>>>(pacc, lpart, hout);
}

extern "C" void kernel_launch(void* const* d_in, const int* in_sizes, int n_in,
                              void* d_out, int out_size, void* d_ws, size_t ws_size,
                              hipStream_t stream) {
    const float* x    = (const float*)d_in[0];
    const int*   adj  = (const int*)d_in[1];
    const float* W1   = (const float*)d_in[2];
    const float* a1   = (const float*)d_in[3];
    const float* W2   = (const float*)d_in[4];
    const float* a2   = (const float*)d_in[5];
    const float* W3   = (const float*)d_in[6];
    const float* a3   = (const float*)d_in[7];
    const float* Wlin = (const float*)d_in[8];
    const float* blin = (const float*)d_in[9];
    float* out = (float*)d_out;

    char* ws = (char*)d_ws;
    uint32_t*       mask = (uint32_t*)ws;                                   // 2 MB
    unsigned short* xbf  = (unsigned short*)(ws + (2u << 20));              // 4 MB
    unsigned short* WhT  = (unsigned short*)(ws + (6u << 20));              // 2 MB
    unsigned short* WT1  = (unsigned short*)(ws + (8u << 20));              // 256 KB
    unsigned short* WT2  = (unsigned short*)(ws + (8u << 20) + (256u << 10)); // 64 KB
    unsigned short* WT3  = (unsigned short*)(ws + (8u << 20) + (320u << 10)); // 16 KB
    float*          f1   = (float*)(ws + (8u << 20) + (384u << 10));        // 64 KB
    float*          f2   = (float*)(ws + (8u << 20) + (448u << 10));        // 64 KB
    float*          lpart= (float*)(ws + (8u << 20) + (512u << 10));        // 256 KB
    float*          pacc = (float*)(ws + (9u << 20));                       // 16 MB

    k_pack<<<65536, 256, 0, stream>>>(adj, (unsigned long long*)mask);
    k_convert<<<2720, 256, 0, stream>>>(x, xbf, W1, WT1, W2, WT2, W3, WT3);

    run_stage<512, 64>(stream, mask, xbf, WT1, a1, WhT, f1, f2, pacc, lpart, xbf);
    run_stage<256, 32>(stream, mask, xbf, WT2, a2, WhT, f1, f2, pacc, lpart, xbf);
    run_stage<128, 16>(stream, mask, xbf, WT3, a3, WhT, f1, f2, pacc, lpart, xbf);

    k_final<<<NNODES / 4, 256, 0, stream>>>(xbf, Wlin, blin, out);
}

// Round 5
// 150.884 us; speedup vs baseline: 2.7450x; 1.0490x over previous
//
#include <hip/hip_runtime.h>
#include <hip/hip_bf16.h>
#include <stdint.h>

typedef __attribute__((ext_vector_type(8))) short short8;
typedef __attribute__((ext_vector_type(4))) float float4v;

#define NHEADS 4
#define NNODES 4096
#define LOG2E 1.4426950408889634f
#define PSTR ((size_t)NHEADS * NNODES * 64)   // partial-accum stride (floats)
#define LSTR ((size_t)NHEADS * NNODES)        // partial-l stride (floats)

__device__ __forceinline__ unsigned short f2b(float x) {
    union { float f; uint32_t u; } v; v.f = x;
    uint32_t u = v.u;
    uint32_t r = (u + 0x7FFFu + ((u >> 16) & 1u)) >> 16;
    return (unsigned short)r;
}
__device__ __forceinline__ float b2f(unsigned short s) {
    union { uint32_t u; float f; } v; v.u = ((uint32_t)s) << 16;
    return v.f;
}
__device__ __forceinline__ uint32_t cvtpk(float lo, float hi) {
    uint32_t r;
    asm("v_cvt_pk_bf16_f32 %0, %1, %2" : "=v"(r) : "v"(lo), "v"(hi));
    return r;
}

#define AS1 __attribute__((address_space(1)))
#define AS3 __attribute__((address_space(3)))
__device__ __forceinline__ void gl_lds16(const void* g, void* l) {
    __builtin_amdgcn_global_load_lds((const AS1 unsigned int*)g,
                                     (AS3 unsigned int*)l, 16, 0, 0);
}

// ---- fused preprocessing: adjacency pack + x cast + W transposes ----
__global__ __launch_bounds__(256) void k_pre(const int* __restrict__ adj,
                                             unsigned long long* __restrict__ mask,
                                             const float* __restrict__ x,
                                             unsigned short* __restrict__ xbf,
                                             const float* __restrict__ W1,
                                             unsigned short* __restrict__ WT1,
                                             const float* __restrict__ W2,
                                             unsigned short* __restrict__ WT2,
                                             const float* __restrict__ W3,
                                             unsigned short* __restrict__ WT3) {
    int b = blockIdx.x;
    if (b < 65536) {                        // pack: 1 word/thread
        int w = (b * 256 + threadIdx.x) >> 6;
        int lane = threadIdx.x & 63;
        int row = w >> 6;
        int chunk = w & 63;
        int j = chunk * 64 + lane;
        int v = adj[(size_t)row * NNODES + j];
        unsigned long long bm = __ballot(v != 0);
        if (lane == 0) mask[row * 64 + chunk] = bm;
        return;
    }
    int i = (b - 65536) * 256 + threadIdx.x;
    if (i < 524288) {                       // x: 4096*512 f32, 4 per thread
        float4v v = ((const float4v*)x)[i];
        uint2 r;
        r.x = cvtpk(v[0], v[1]);
        r.y = cvtpk(v[2], v[3]);
        ((uint2*)xbf)[i] = r;
    } else if (i < 524288 + 131072) {       // W1 [4][512][64] -> WT1 [4][64][512]
        int j = i - 524288;
        int o = j & 63, f = (j >> 6) & 511, h = j >> 15;
        WT1[((size_t)(h * 64 + o)) * 512 + f] = f2b(W1[j]);
    } else if (i < 524288 + 131072 + 32768) { // W2 [4][256][32] -> WT2 [4][32][256]
        int j = i - 655360;
        int o = j & 31, f = (j >> 5) & 255, h = j >> 13;
        WT2[((size_t)(h * 32 + o)) * 256 + f] = f2b(W2[j]);
    } else if (i < 524288 + 131072 + 32768 + 8192) { // W3 [4][128][16] -> WT3 [4][16][128]
        int j = i - 688128;
        int o = j & 15, f = (j >> 4) & 127, h = j >> 11;
        WT3[((size_t)(h * 16 + o)) * 128 + f] = f2b(W3[j]);
    }
}

// ---- Wh = x @ W (4-wave K-split) + fused f1/f2 epilogue; writes WhT bf16 only ----
template <int Fin, int O>
__global__ __launch_bounds__(256) void k_whgemm(const unsigned short* __restrict__ A,
                                                const unsigned short* __restrict__ WT,
                                                const float* __restrict__ avec,
                                                unsigned short* __restrict__ WhT,
                                                float* __restrict__ f1,
                                                float* __restrict__ f2) {
    __shared__ float scc[4][16][64];
    constexpr int HPB = 64 / O;           // complete heads per col-group
    const int rt = blockIdx.x & 255, cg = blockIdx.x >> 8;
    const int wv = threadIdx.x >> 6, lane = threadIdx.x & 63;
    const int il = lane & 15, g = lane >> 4;
    constexpr int kpw = Fin >> 2;
    const int k0 = wv * kpw;
    float4v acc[4];
#pragma unroll
    for (int ot = 0; ot < 4; ++ot) acc[ot] = (float4v){0.f, 0.f, 0.f, 0.f};
    const unsigned short* Arow = A + (size_t)(rt * 16 + il) * Fin + k0 + 8 * g;
    const unsigned short* Bcol = WT + (size_t)(cg * 64 + il) * Fin + k0 + 8 * g;
#pragma unroll
    for (int k = 0; k < kpw; k += 32) {
        short8 af = *(const short8*)(Arow + k);
#pragma unroll
        for (int ot = 0; ot < 4; ++ot) {
            short8 bf = *(const short8*)(Bcol + (size_t)ot * 16 * Fin + k);
            acc[ot] = __builtin_amdgcn_mfma_f32_16x16x32_bf16(af, bf, acc[ot], 0, 0, 0);
        }
    }
#pragma unroll
    for (int ot = 0; ot < 4; ++ot)
#pragma unroll
        for (int r = 0; r < 4; ++r) scc[wv][g * 4 + r][ot * 16 + il] = acc[ot][r];
    __syncthreads();
    // epilogue 1: WhT bf16 [H][O][N]
    for (int e = threadIdx.x; e < 1024; e += 256) {
        int row = e >> 6, col = e & 63;
        float v = scc[0][row][col] + scc[1][row][col] + scc[2][row][col] + scc[3][row][col];
        int gc = cg * 64 + col;
        int hh = gc / O, o = gc % O;
        WhT[((size_t)(hh * O + o)) * NNODES + rt * 16 + row] = f2b(v);
    }
    // epilogue 2: f1/f2 (each block covers complete heads -> no atomics)
    {
        int hl = lane / O, o = lane % O;
        int h = cg * HPB + hl;
        float av1 = avec[h * 2 * O + o];
        float av2 = avec[h * 2 * O + O + o];
#pragma unroll
        for (int r = 0; r < 4; ++r) {
            int row = wv * 4 + r;
            float v = scc[0][row][lane] + scc[1][row][lane] + scc[2][row][lane] + scc[3][row][lane];
            float s1 = v * av1, s2 = v * av2;
#pragma unroll
            for (int d = O / 2; d > 0; d >>= 1) {
                s1 += __shfl_xor(s1, d);
                s2 += __shfl_xor(s2, d);
            }
            if (o == 0) {
                int n = rt * 16 + row;
                f1[h * NNODES + n] = s1 * LOG2E;
                f2[h * NNODES + n] = s2 * LOG2E;
            }
        }
    }
}

// ---- stage one 64-j B tile ([O rows][64 j] bf16) into LDS, source-swizzled ----
template <int O>
__device__ __forceinline__ void stage_tile(const unsigned short* WB0, int j0,
                                           char* dst, int tid) {
    constexpr int CH = O * 8;   // 16B chunks
#pragma unroll
    for (int q = 0; q < CH; q += 256) {
        int s = q + tid;
        if (CH >= 256 || s < CH) {
            int o = s >> 3, c = s & 7;
            int cg = c ^ (o & 7);
            gl_lds16(WB0 + (size_t)o * NNODES + j0 + 8 * cg, dst + s * 16);
        }
    }
}

// ---- fused attention PV: 3-buffer counted-vmcnt pipeline (T4), disjoint j-split ----
template <int O>
__global__ __launch_bounds__(256, 4) void k_pv(const uint32_t* __restrict__ mask,
                                               const float* __restrict__ f1L,
                                               const float* __restrict__ f2L,
                                               const unsigned short* __restrict__ WhT,
                                               float* __restrict__ pacc,
                                               float* __restrict__ lpart) {
    constexpr int NT = O / 16;
    constexpr int CH = O * 8;
    constexpr int LPT = (O == 64) ? 2 : 1;   // global_load_lds per thread per tile
    __shared__ unsigned short bt[3][CH * 8];
    __shared__ float sf2[1024];
    __shared__ uint32_t smask[64][34];       // pad 34 -> conflict-free b64 reads
    const int b = blockIdx.x;
    const int js = b & 3, rt = (b >> 2) & 63, h = b >> 8;
    const int tid = threadIdx.x, wv = tid >> 6, lane = tid & 63;
    const int il = lane & 15, g = lane >> 4;
    const int j0b = js * 1024;
    const float* f2h = f2L + h * NNODES;
    const unsigned short* WB0 = WhT + (size_t)h * O * NNODES;
    const int nrow = wv * 16 + il;
    const float f1i = f1L[h * NNODES + rt * 64 + nrow];

    // ---- prologue: masks -> regs, drain, masks -> LDS, then the ONLY in-flight vm ops are stages
    {
        int r = tid >> 2, c = (tid & 3) * 8;
        const uint32_t* mg = mask + (size_t)(rt * 64 + r) * 128 + js * 32 + c;
        uint4 m0 = *(const uint4*)mg;
        uint4 m1 = *(const uint4*)(mg + 4);
        asm volatile("s_waitcnt vmcnt(0)" ::: "memory");
        uint32_t* dstm = &smask[r][c];
        *(uint2*)(dstm + 0) = make_uint2(m0.x, m0.y);
        *(uint2*)(dstm + 2) = make_uint2(m0.z, m0.w);
        *(uint2*)(dstm + 4) = make_uint2(m1.x, m1.y);
        *(uint2*)(dstm + 6) = make_uint2(m1.z, m1.w);
    }
    gl_lds16(f2h + j0b + tid * 4, (char*)sf2 + tid * 16);
    stage_tile<O>(WB0, j0b, (char*)&bt[0][0], tid);
    stage_tile<O>(WB0, j0b + 64, (char*)&bt[1][0], tid);
    asm volatile("s_waitcnt vmcnt(%0) lgkmcnt(0)" :: "i"(LPT) : "memory");
    __builtin_amdgcn_sched_barrier(0);
    __builtin_amdgcn_s_barrier();

    float4v acc[NT];
#pragma unroll
    for (int ot = 0; ot < NT; ++ot) acc[ot] = (float4v){0.f, 0.f, 0.f, 0.f};
    float4v accl = (float4v){0.f, 0.f, 0.f, 0.f};
    short8 bones;
#pragma unroll
    for (int q = 0; q < 8; ++q) bones[q] = (il == 0) ? (short)0x3F80 : (short)0;

    auto compute = [&](int t, const char* btc) {
        uint2 mw = *(const uint2*)&smask[nrow][2 * t];
        const float* fp0 = sf2 + t * 64 + 8 * g;
#pragma unroll
        for (int s = 0; s < 2; ++s) {
            short8 B[NT];
#pragma unroll
            for (int ot = 0; ot < NT; ++ot) {
                int o = ot * 16 + il;
                B[ot] = *(const short8*)(btc + o * 128 + 16 * (((s << 2) + g) ^ (il & 7)));
            }
            const float* fp = fp0 + s * 32;
            float4v fa = *(const float4v*)fp;
            float4v fb = *(const float4v*)(fp + 4);
            uint32_t word = s ? mw.y : mw.x;
            uint32_t bits = (word >> (8 * g)) & 0xFFu;
            float p[8];
#pragma unroll
            for (int bb = 0; bb < 8; ++bb) {
                float sv = f1i + ((bb < 4) ? fa[bb] : fb[bb - 4]);
                sv = fmaxf(sv, 0.2f * sv);
                float pv = __builtin_amdgcn_exp2f(sv);
                p[bb] = ((bits >> bb) & 1u) ? pv : 0.f;
            }
            union { short8 s8; uint32_t u[4]; } pu;
            pu.u[0] = cvtpk(p[0], p[1]);
            pu.u[1] = cvtpk(p[2], p[3]);
            pu.u[2] = cvtpk(p[4], p[5]);
            pu.u[3] = cvtpk(p[6], p[7]);
#pragma unroll
            for (int ot = 0; ot < NT; ++ot)
                acc[ot] = __builtin_amdgcn_mfma_f32_16x16x32_bf16(pu.s8, B[ot], acc[ot], 0, 0, 0);
            accl = __builtin_amdgcn_mfma_f32_16x16x32_bf16(pu.s8, bones, accl, 0, 0, 0);
        }
    };

    for (int t = 0; t < 14; ++t) {
        stage_tile<O>(WB0, j0b + (t + 2) * 64, (char*)&bt[(t + 2) % 3][0], tid);
        compute(t, (const char*)&bt[t % 3][0]);
        asm volatile("s_waitcnt vmcnt(%0)" :: "i"(LPT) : "memory");
        __builtin_amdgcn_sched_barrier(0);
        __builtin_amdgcn_s_barrier();
    }
    compute(14, (const char*)&bt[2][0]);
    asm volatile("s_waitcnt vmcnt(0)" ::: "memory");
    __builtin_amdgcn_sched_barrier(0);
    __builtin_amdgcn_s_barrier();
    compute(15, (const char*)&bt[0][0]);

    // non-atomic disjoint partial stores (slice js owns its buffer)
    float* pj = pacc + js * PSTR + (size_t)h * NNODES * O;
#pragma unroll
    for (int ot = 0; ot < NT; ++ot)
#pragma unroll
        for (int r = 0; r < 4; ++r)
            pj[(size_t)(rt * 64 + wv * 16 + g * 4 + r) * O + ot * 16 + il] = acc[ot][r];
    if (il == 0) {
        float* lj = lpart + js * LSTR + h * NNODES;
#pragma unroll
        for (int r = 0; r < 4; ++r)
            lj[rt * 64 + wv * 16 + g * 4 + r] = accl[r];
    }
}

// ---- finalize: sum 4 partials, divide, elu, head-concat to bf16 ----
template <int O>
__global__ __launch_bounds__(256) void k_fin(const float* __restrict__ pacc,
                                             const float* __restrict__ lpart,
                                             unsigned short* __restrict__ hout) {
    constexpr int HO = NHEADS * O;
    int e = blockIdx.x * 256 + threadIdx.x;
    int o = e % O;
    int n = (e / O) & (NNODES - 1);
    int h = e / (O * NNODES);
    size_t idx = ((size_t)h * NNODES + n) * O + o;
    float s = pacc[idx] + pacc[PSTR + idx] + pacc[2 * PSTR + idx] + pacc[3 * PSTR + idx];
    int li = h * NNODES + n;
    float l = lpart[li] + lpart[LSTR + li] + lpart[2 * LSTR + li] + lpart[3 * LSTR + li];
    float v = s / l;
    v = (v > 0.f) ? v : (__expf(v) - 1.f);
    hout[(size_t)n * HO + h * O + o] = f2b(v);
}

// ---- logits = h3 @ Wlin + blin; log_softmax ----
__global__ __launch_bounds__(256) void k_final(const unsigned short* __restrict__ h3,
                                               const float* __restrict__ Wlin,
                                               const float* __restrict__ blin,
                                               float* __restrict__ out) {
    int n = blockIdx.x * 4 + (threadIdx.x >> 6);
    int lane = threadIdx.x & 63;
    float logit = 0.f;
    if (lane < 40) {
        logit = blin[lane];
        for (int k = 0; k < 64; ++k) {
            logit += b2f(h3[n * 64 + k]) * Wlin[k * 40 + lane];
        }
    }
    float mv = (lane < 40) ? logit : -3.0e38f;
    for (int d = 32; d > 0; d >>= 1) mv = fmaxf(mv, __shfl_xor(mv, d));
    float ex = (lane < 40) ? __expf(logit - mv) : 0.f;
    for (int d = 32; d > 0; d >>= 1) ex += __shfl_xor(ex, d);
    if (lane < 40) out[n * 40 + lane] = logit - mv - logf(ex);
}

template <int Fin, int O>
static void run_stage(hipStream_t stream, const uint32_t* mask, const unsigned short* xin,
                      const unsigned short* WT, const float* avec,
                      unsigned short* WhT, float* f1, float* f2,
                      float* pacc, float* lpart, unsigned short* hout) {
    constexpr int CG = (NHEADS * O) / 64;
    k_whgemm<Fin, O><<<256 * CG, 256, 0, stream>>>(xin, WT, avec, WhT, f1, f2);
    k_pv<O><<<1024, 256, 0, stream>>>(mask, f1, f2, WhT, pacc, lpart);
    k_fin<O><<<NHEADS * NNODES * O / 256, 256, 0, stream>>>(pacc, lpart, hout);
}

extern "C" void kernel_launch(void* const* d_in, const int* in_sizes, int n_in,
                              void* d_out, int out_size, void* d_ws, size_t ws_size,
                              hipStream_t stream) {
    const float* x    = (const float*)d_in[0];
    const int*   adj  = (const int*)d_in[1];
    const float* W1   = (const float*)d_in[2];
    const float* a1   = (const float*)d_in[3];
    const float* W2   = (const float*)d_in[4];
    const float* a2   = (const float*)d_in[5];
    const float* W3   = (const float*)d_in[6];
    const float* a3   = (const float*)d_in[7];
    const float* Wlin = (const float*)d_in[8];
    const float* blin = (const float*)d_in[9];
    float* out = (float*)d_out;

    char* ws = (char*)d_ws;
    uint32_t*       mask = (uint32_t*)ws;                                   // 2 MB
    unsigned short* xbf  = (unsigned short*)(ws + (2u << 20));              // 4 MB
    unsigned short* WhT  = (unsigned short*)(ws + (6u << 20));              // 2 MB
    unsigned short* WT1  = (unsigned short*)(ws + (8u << 20));              // 256 KB
    unsigned short* WT2  = (unsigned short*)(ws + (8u << 20) + (256u << 10)); // 64 KB
    unsigned short* WT3  = (unsigned short*)(ws + (8u << 20) + (320u << 10)); // 16 KB
    float*          f1   = (float*)(ws + (8u << 20) + (384u << 10));        // 64 KB
    float*          f2   = (float*)(ws + (8u << 20) + (448u << 10));        // 64 KB
    float*          lpart= (float*)(ws + (8u << 20) + (512u << 10));        // 256 KB
    float*          pacc = (float*)(ws + (9u << 20));                       // 16 MB

    k_pre<<<65536 + 2720, 256, 0, stream>>>(adj, (unsigned long long*)mask, x, xbf,
                                            W1, WT1, W2, WT2, W3, WT3);

    run_stage<512, 64>(stream, mask, xbf, WT1, a1, WhT, f1, f2, pacc, lpart, xbf);
    run_stage<256, 32>(stream, mask, xbf, WT2, a2, WhT, f1, f2, pacc, lpart, xbf);
    run_stage<128, 16>(stream, mask, xbf, WT3, a3, WhT, f1, f2, pacc, lpart, xbf);

    k_final<<<NNODES / 4, 256, 0, stream>>>(xbf, Wlin, blin, out);
}

// Round 6
// 134.409 us; speedup vs baseline: 3.0815x; 1.1226x over previous
//
#include <hip/hip_runtime.h>
#include <hip/hip_bf16.h>
#include <stdint.h>

typedef __attribute__((ext_vector_type(8))) short short8;
typedef __attribute__((ext_vector_type(4))) float float4v;

#define NHEADS 4
#define NNODES 4096
#define LOG2E 1.4426950408889634f
#define PSTR ((size_t)NHEADS * NNODES * 64)   // partial-accum stride (floats)
#define LSTR ((size_t)NHEADS * NNODES)        // partial-l stride (floats)

__device__ __forceinline__ unsigned short f2b(float x) {
    union { float f; uint32_t u; } v; v.f = x;
    uint32_t u = v.u;
    uint32_t r = (u + 0x7FFFu + ((u >> 16) & 1u)) >> 16;
    return (unsigned short)r;
}
__device__ __forceinline__ float b2f(unsigned short s) {
    union { uint32_t u; float f; } v; v.u = ((uint32_t)s) << 16;
    return v.f;
}
__device__ __forceinline__ uint32_t cvtpk(float lo, float hi) {
    uint32_t r;
    asm("v_cvt_pk_bf16_f32 %0, %1, %2" : "=v"(r) : "v"(lo), "v"(hi));
    return r;
}

#define AS1 __attribute__((address_space(1)))
#define AS3 __attribute__((address_space(3)))
__device__ __forceinline__ void gl_lds16(const void* g, void* l) {
    __builtin_amdgcn_global_load_lds((const AS1 unsigned int*)g,
                                     (AS3 unsigned int*)l, 16, 0, 0);
}

// ---- fused preprocessing: ballot-free adjacency pack + x cast + W transposes ----
__global__ __launch_bounds__(256) void k_pre(const int* __restrict__ adj,
                                             unsigned short* __restrict__ mask16,
                                             const float* __restrict__ x,
                                             unsigned short* __restrict__ xbf,
                                             const float* __restrict__ W1,
                                             unsigned short* __restrict__ WT1,
                                             const float* __restrict__ W2,
                                             unsigned short* __restrict__ WT2,
                                             const float* __restrict__ W3,
                                             unsigned short* __restrict__ WT3) {
    int b = blockIdx.x;
    if (b < 4096) {                         // pack: 16 consecutive j per thread, no ballot
        const int4* ap = (const int4*)(adj + ((size_t)b << 12)) + threadIdx.x * 4;
        int4 a0 = ap[0], a1 = ap[1], a2 = ap[2], a3 = ap[3];
        int v[16] = {a0.x, a0.y, a0.z, a0.w, a1.x, a1.y, a1.z, a1.w,
                     a2.x, a2.y, a2.z, a2.w, a3.x, a3.y, a3.z, a3.w};
        uint32_t bits = 0;
#pragma unroll
        for (int k = 0; k < 16; ++k) bits |= (uint32_t)(v[k] != 0) << k;
        mask16[(b << 8) + threadIdx.x] = (unsigned short)bits;
        return;
    }
    int i = (b - 4096) * 256 + threadIdx.x;
    if (i < 524288) {                       // x: 4096*512 f32, 4 per thread
        float4v v = ((const float4v*)x)[i];
        uint2 r;
        r.x = cvtpk(v[0], v[1]);
        r.y = cvtpk(v[2], v[3]);
        ((uint2*)xbf)[i] = r;
    } else if (i < 524288 + 131072) {       // W1 [4][512][64] -> WT1 [4][64][512]
        int j = i - 524288;
        int o = j & 63, f = (j >> 6) & 511, h = j >> 15;
        WT1[((size_t)(h * 64 + o)) * 512 + f] = f2b(W1[j]);
    } else if (i < 524288 + 131072 + 32768) { // W2 [4][256][32] -> WT2 [4][32][256]
        int j = i - 655360;
        int o = j & 31, f = (j >> 5) & 255, h = j >> 13;
        WT2[((size_t)(h * 32 + o)) * 256 + f] = f2b(W2[j]);
    } else if (i < 524288 + 131072 + 32768 + 8192) { // W3 [4][128][16] -> WT3 [4][16][128]
        int j = i - 688128;
        int o = j & 15, f = (j >> 4) & 127, h = j >> 11;
        WT3[((size_t)(h * 16 + o)) * 128 + f] = f2b(W3[j]);
    }
}

// ---- Wh = x @ W (4-wave K-split) + fused f1/f2 epilogue; writes WhT bf16 only ----
template <int Fin, int O>
__global__ __launch_bounds__(256) void k_whgemm(const unsigned short* __restrict__ A,
                                                const unsigned short* __restrict__ WT,
                                                const float* __restrict__ avec,
                                                unsigned short* __restrict__ WhT,
                                                float* __restrict__ f1,
                                                float* __restrict__ f2) {
    __shared__ float scc[4][16][64];
    constexpr int HPB = 64 / O;           // complete heads per col-group
    const int rt = blockIdx.x & 255, cg = blockIdx.x >> 8;
    const int wv = threadIdx.x >> 6, lane = threadIdx.x & 63;
    const int il = lane & 15, g = lane >> 4;
    constexpr int kpw = Fin >> 2;
    const int k0 = wv * kpw;
    float4v acc[4];
#pragma unroll
    for (int ot = 0; ot < 4; ++ot) acc[ot] = (float4v){0.f, 0.f, 0.f, 0.f};
    const unsigned short* Arow = A + (size_t)(rt * 16 + il) * Fin + k0 + 8 * g;
    const unsigned short* Bcol = WT + (size_t)(cg * 64 + il) * Fin + k0 + 8 * g;
#pragma unroll
    for (int k = 0; k < kpw; k += 32) {
        short8 af = *(const short8*)(Arow + k);
#pragma unroll
        for (int ot = 0; ot < 4; ++ot) {
            short8 bf = *(const short8*)(Bcol + (size_t)ot * 16 * Fin + k);
            acc[ot] = __builtin_amdgcn_mfma_f32_16x16x32_bf16(af, bf, acc[ot], 0, 0, 0);
        }
    }
#pragma unroll
    for (int ot = 0; ot < 4; ++ot)
#pragma unroll
        for (int r = 0; r < 4; ++r) scc[wv][g * 4 + r][ot * 16 + il] = acc[ot][r];
    __syncthreads();
    // epilogue 1: WhT bf16 [H][O][N]
    for (int e = threadIdx.x; e < 1024; e += 256) {
        int row = e >> 6, col = e & 63;
        float v = scc[0][row][col] + scc[1][row][col] + scc[2][row][col] + scc[3][row][col];
        int gc = cg * 64 + col;
        int hh = gc / O, o = gc % O;
        WhT[((size_t)(hh * O + o)) * NNODES + rt * 16 + row] = f2b(v);
    }
    // epilogue 2: f1/f2 (each block covers complete heads -> no atomics)
    {
        int hl = lane / O, o = lane % O;
        int h = cg * HPB + hl;
        float av1 = avec[h * 2 * O + o];
        float av2 = avec[h * 2 * O + O + o];
#pragma unroll
        for (int r = 0; r < 4; ++r) {
            int row = wv * 4 + r;
            float v = scc[0][row][lane] + scc[1][row][lane] + scc[2][row][lane] + scc[3][row][lane];
            float s1 = v * av1, s2 = v * av2;
#pragma unroll
            for (int d = O / 2; d > 0; d >>= 1) {
                s1 += __shfl_xor(s1, d);
                s2 += __shfl_xor(s2, d);
            }
            if (o == 0) {
                int n = rt * 16 + row;
                f1[h * NNODES + n] = s1 * LOG2E;
                f2[h * NNODES + n] = s2 * LOG2E;
            }
        }
    }
}

// ---- stage one 64-j B tile ([O rows][64 j] bf16) into LDS, source-swizzled ----
template <int O>
__device__ __forceinline__ void stage_tile(const unsigned short* WB0, int j0,
                                           char* dst, int tid) {
    constexpr int CH = O * 8;   // 16B chunks
#pragma unroll
    for (int q = 0; q < CH; q += 256) {
        int s = q + tid;
        if (CH >= 256 || s < CH) {
            int o = s >> 3, c = s & 7;
            int cg = c ^ (o & 7);
            gl_lds16(WB0 + (size_t)o * NNODES + j0 + 8 * cg, dst + s * 16);
        }
    }
}

// ---- fused attention PV: 3-buffer counted-vmcnt pipeline (T4), disjoint j-split ----
template <int O>
__global__ __launch_bounds__(256, 4) void k_pv(const uint32_t* __restrict__ mask,
                                               const float* __restrict__ f1L,
                                               const float* __restrict__ f2L,
                                               const unsigned short* __restrict__ WhT,
                                               float* __restrict__ pacc,
                                               float* __restrict__ lpart) {
    constexpr int NT = O / 16;
    constexpr int CH = O * 8;
    constexpr int LPT = (O == 64) ? 2 : 1;   // global_load_lds per thread per tile
    __shared__ unsigned short bt[3][CH * 8];
    __shared__ float sf2[1024];
    __shared__ uint32_t smask[64][34];       // pad 34 -> conflict-free b64 reads
    const int b = blockIdx.x;
    const int js = b & 3, rt = (b >> 2) & 63, h = b >> 8;
    const int tid = threadIdx.x, wv = tid >> 6, lane = tid & 63;
    const int il = lane & 15, g = lane >> 4;
    const int j0b = js * 1024;
    const float* f2h = f2L + h * NNODES;
    const unsigned short* WB0 = WhT + (size_t)h * O * NNODES;
    const int nrow = wv * 16 + il;
    const float f1i = f1L[h * NNODES + rt * 64 + nrow];

    // ---- prologue: masks -> regs, drain, masks -> LDS, then the ONLY in-flight vm ops are stages
    {
        int r = tid >> 2, c = (tid & 3) * 8;
        const uint32_t* mg = mask + (size_t)(rt * 64 + r) * 128 + js * 32 + c;
        uint4 m0 = *(const uint4*)mg;
        uint4 m1 = *(const uint4*)(mg + 4);
        asm volatile("s_waitcnt vmcnt(0)" ::: "memory");
        uint32_t* dstm = &smask[r][c];
        *(uint2*)(dstm + 0) = make_uint2(m0.x, m0.y);
        *(uint2*)(dstm + 2) = make_uint2(m0.z, m0.w);
        *(uint2*)(dstm + 4) = make_uint2(m1.x, m1.y);
        *(uint2*)(dstm + 6) = make_uint2(m1.z, m1.w);
    }
    gl_lds16(f2h + j0b + tid * 4, (char*)sf2 + tid * 16);
    stage_tile<O>(WB0, j0b, (char*)&bt[0][0], tid);
    stage_tile<O>(WB0, j0b + 64, (char*)&bt[1][0], tid);
    asm volatile("s_waitcnt vmcnt(%0) lgkmcnt(0)" :: "i"(LPT) : "memory");
    __builtin_amdgcn_sched_barrier(0);
    __builtin_amdgcn_s_barrier();

    float4v acc[NT];
#pragma unroll
    for (int ot = 0; ot < NT; ++ot) acc[ot] = (float4v){0.f, 0.f, 0.f, 0.f};
    float4v accl = (float4v){0.f, 0.f, 0.f, 0.f};
    short8 bones;
#pragma unroll
    for (int q = 0; q < 8; ++q) bones[q] = (il == 0) ? (short)0x3F80 : (short)0;

    auto compute = [&](int t, const char* btc) {
        uint2 mw = *(const uint2*)&smask[nrow][2 * t];
        const float* fp0 = sf2 + t * 64 + 8 * g;
#pragma unroll
        for (int s = 0; s < 2; ++s) {
            short8 B[NT];
#pragma unroll
            for (int ot = 0; ot < NT; ++ot) {
                int o = ot * 16 + il;
                B[ot] = *(const short8*)(btc + o * 128 + 16 * (((s << 2) + g) ^ (il & 7)));
            }
            const float* fp = fp0 + s * 32;
            float4v fa = *(const float4v*)fp;
            float4v fb = *(const float4v*)(fp + 4);
            uint32_t word = s ? mw.y : mw.x;
            uint32_t bits = (word >> (8 * g)) & 0xFFu;
            float p[8];
#pragma unroll
            for (int bb = 0; bb < 8; ++bb) {
                float sv = f1i + ((bb < 4) ? fa[bb] : fb[bb - 4]);
                sv = fmaxf(sv, 0.2f * sv);
                float pv = __builtin_amdgcn_exp2f(sv);
                p[bb] = ((bits >> bb) & 1u) ? pv : 0.f;
            }
            union { short8 s8; uint32_t u[4]; } pu;
            pu.u[0] = cvtpk(p[0], p[1]);
            pu.u[1] = cvtpk(p[2], p[3]);
            pu.u[2] = cvtpk(p[4], p[5]);
            pu.u[3] = cvtpk(p[6], p[7]);
#pragma unroll
            for (int ot = 0; ot < NT; ++ot)
                acc[ot] = __builtin_amdgcn_mfma_f32_16x16x32_bf16(pu.s8, B[ot], acc[ot], 0, 0, 0);
            accl = __builtin_amdgcn_mfma_f32_16x16x32_bf16(pu.s8, bones, accl, 0, 0, 0);
        }
    };

    for (int t = 0; t < 14; ++t) {
        stage_tile<O>(WB0, j0b + (t + 2) * 64, (char*)&bt[(t + 2) % 3][0], tid);
        compute(t, (const char*)&bt[t % 3][0]);
        asm volatile("s_waitcnt vmcnt(%0)" :: "i"(LPT) : "memory");
        __builtin_amdgcn_sched_barrier(0);
        __builtin_amdgcn_s_barrier();
    }
    compute(14, (const char*)&bt[2][0]);
    asm volatile("s_waitcnt vmcnt(0)" ::: "memory");
    __builtin_amdgcn_sched_barrier(0);
    __builtin_amdgcn_s_barrier();
    compute(15, (const char*)&bt[0][0]);

    // non-atomic disjoint partial stores (slice js owns its buffer)
    float* pj = pacc + js * PSTR + (size_t)h * NNODES * O;
#pragma unroll
    for (int ot = 0; ot < NT; ++ot)
#pragma unroll
        for (int r = 0; r < 4; ++r)
            pj[(size_t)(rt * 64 + wv * 16 + g * 4 + r) * O + ot * 16 + il] = acc[ot][r];
    if (il == 0) {
        float* lj = lpart + js * LSTR + h * NNODES;
#pragma unroll
        for (int r = 0; r < 4; ++r)
            lj[rt * 64 + wv * 16 + g * 4 + r] = accl[r];
    }
}

// ---- finalize (stages 1,2): sum 4 partials, divide, elu, head-concat to bf16 ----
template <int O>
__global__ __launch_bounds__(256) void k_fin(const float* __restrict__ pacc,
                                             const float* __restrict__ lpart,
                                             unsigned short* __restrict__ hout) {
    constexpr int HO = NHEADS * O;
    int e = blockIdx.x * 256 + threadIdx.x;
    int o = e % O;
    int n = (e / O) & (NNODES - 1);
    int h = e / (O * NNODES);
    size_t idx = ((size_t)h * NNODES + n) * O + o;
    float s = pacc[idx] + pacc[PSTR + idx] + pacc[2 * PSTR + idx] + pacc[3 * PSTR + idx];
    int li = h * NNODES + n;
    float l = lpart[li] + lpart[LSTR + li] + lpart[2 * LSTR + li] + lpart[3 * LSTR + li];
    float v = s / l;
    v = (v > 0.f) ? v : (__expf(v) - 1.f);
    hout[(size_t)n * HO + h * O + o] = f2b(v);
}

// ---- stage-3 finalize fused with final linear + log_softmax (LDS handoff) ----
__global__ __launch_bounds__(256) void k_fin3final(const float* __restrict__ pacc,
                                                   const float* __restrict__ lpart,
                                                   const float* __restrict__ Wlin,
                                                   const float* __restrict__ blin,
                                                   float* __restrict__ out) {
    __shared__ float sh3[4][64];
    const int tid = threadIdx.x;
    const int n0 = blockIdx.x * 4;
    {   // finalize 4 rows x 64 features (h*16+o), one element per thread
        int r = tid >> 6, hh = (tid >> 4) & 3, o = tid & 15;
        int n = n0 + r;
        size_t idx = ((size_t)hh * NNODES + n) * 16 + o;
        float s = pacc[idx] + pacc[PSTR + idx] + pacc[2 * PSTR + idx] + pacc[3 * PSTR + idx];
        int li = hh * NNODES + n;
        float l = lpart[li] + lpart[LSTR + li] + lpart[2 * LSTR + li] + lpart[3 * LSTR + li];
        float v = s / l;
        v = (v > 0.f) ? v : (__expf(v) - 1.f);
        sh3[r][hh * 16 + o] = v;
    }
    __syncthreads();
    int rr = tid >> 6, lane = tid & 63;
    int n = n0 + rr;
    float logit = 0.f;
    if (lane < 40) {
        logit = blin[lane];
#pragma unroll
        for (int k = 0; k < 64; ++k) logit += sh3[rr][k] * Wlin[k * 40 + lane];
    }
    float mv = (lane < 40) ? logit : -3.0e38f;
    for (int d = 32; d > 0; d >>= 1) mv = fmaxf(mv, __shfl_xor(mv, d));
    float ex = (lane < 40) ? __expf(logit - mv) : 0.f;
    for (int d = 32; d > 0; d >>= 1) ex += __shfl_xor(ex, d);
    if (lane < 40) out[n * 40 + lane] = logit - mv - logf(ex);
}

template <int Fin, int O>
static void run_stage(hipStream_t stream, const uint32_t* mask, const unsigned short* xin,
                      const unsigned short* WT, const float* avec,
                      unsigned short* WhT, float* f1, float* f2,
                      float* pacc, float* lpart) {
    constexpr int CG = (NHEADS * O) / 64;
    k_whgemm<Fin, O><<<256 * CG, 256, 0, stream>>>(xin, WT, avec, WhT, f1, f2);
    k_pv<O><<<1024, 256, 0, stream>>>(mask, f1, f2, WhT, pacc, lpart);
}

extern "C" void kernel_launch(void* const* d_in, const int* in_sizes, int n_in,
                              void* d_out, int out_size, void* d_ws, size_t ws_size,
                              hipStream_t stream) {
    const float* x    = (const float*)d_in[0];
    const int*   adj  = (const int*)d_in[1];
    const float* W1   = (const float*)d_in[2];
    const float* a1   = (const float*)d_in[3];
    const float* W2   = (const float*)d_in[4];
    const float* a2   = (const float*)d_in[5];
    const float* W3   = (const float*)d_in[6];
    const float* a3   = (const float*)d_in[7];
    const float* Wlin = (const float*)d_in[8];
    const float* blin = (const float*)d_in[9];
    float* out = (float*)d_out;

    char* ws = (char*)d_ws;
    uint32_t*       mask = (uint32_t*)ws;                                   // 2 MB
    unsigned short* xbf  = (unsigned short*)(ws + (2u << 20));              // 4 MB
    unsigned short* WhT  = (unsigned short*)(ws + (6u << 20));              // 2 MB
    unsigned short* WT1  = (unsigned short*)(ws + (8u << 20));              // 256 KB
    unsigned short* WT2  = (unsigned short*)(ws + (8u << 20) + (256u << 10)); // 64 KB
    unsigned short* WT3  = (unsigned short*)(ws + (8u << 20) + (320u << 10)); // 16 KB
    float*          f1   = (float*)(ws + (8u << 20) + (384u << 10));        // 64 KB
    float*          f2   = (float*)(ws + (8u << 20) + (448u << 10));        // 64 KB
    float*          lpart= (float*)(ws + (8u << 20) + (512u << 10));        // 256 KB
    float*          pacc = (float*)(ws + (9u << 20));                       // 16 MB

    k_pre<<<4096 + 2720, 256, 0, stream>>>(adj, (unsigned short*)mask, x, xbf,
                                           W1, WT1, W2, WT2, W3, WT3);

    run_stage<512, 64>(stream, mask, xbf, WT1, a1, WhT, f1, f2, pacc, lpart);
    k_fin<64><<<NHEADS * NNODES * 64 / 256, 256, 0, stream>>>(pacc, lpart, xbf);
    run_stage<256, 32>(stream, mask, xbf, WT2, a2, WhT, f1, f2, pacc, lpart);
    k_fin<32><<<NHEADS * NNODES * 32 / 256, 256, 0, stream>>>(pacc, lpart, xbf);
    run_stage<128, 16>(stream, mask, xbf, WT3, a3, WhT, f1, f2, pacc, lpart);
    k_fin3final<<<NNODES / 4, 256, 0, stream>>>(pacc, lpart, Wlin, blin, out);
}